// Round 5
// baseline (337.631 us; speedup 1.0000x reference)
//
#include <hip/hip_runtime.h>
#include <math.h>

#define SS 1024
#define NC 8
#define BWD 170
#define THRESH 1e-4f

typedef unsigned long long ull;

__device__ __forceinline__ float2 cmul(float2 a, float2 b) {
    return make_float2(a.x * b.x - a.y * b.y, a.x * b.y + a.y * b.x);
}

// ---------------------------------------------------------------------------
// Blur + alpha blend + pack. Two-stage separable filter, 32x32 output tile,
// interior (alpha==1) fast path. Z[c][y][x] = lms_e + i * fuse_e
// ---------------------------------------------------------------------------
__global__ __launch_bounds__(256) void blur_pack_kernel(
        const float* __restrict__ lms, const float* __restrict__ fuse,
        float2* __restrict__ Z) {
    int c = blockIdx.z;
    int bx = blockIdx.x * 32, by = blockIdx.y * 32;
    int tid = threadIdx.x;
    const float* L = lms + ((size_t)c << 20);
    const float* F = fuse + ((size_t)c << 20);
    float2* Zc = Z + ((size_t)c << 20);

    // alpha==1 iff row,col in [BWD, SS-1-BWD]; block-uniform fast path
    bool fast = (bx >= BWD) && (bx + 31 <= SS - 1 - BWD) &&
                (by >= BWD) && (by + 31 <= SS - 1 - BWD);
    if (fast) {
        int r = tid >> 3, g = (tid & 7) * 4;
        int y = by + r, x = bx + g;
        float4 lv = *(const float4*)&L[((size_t)y << 10) + x];
        float4 fv = *(const float4*)&F[((size_t)y << 10) + x];
        float2* zp = &Zc[((size_t)y << 10) + x];
        *(float4*)&zp[0] = make_float4(lv.x, fv.x, lv.y, fv.y);
        *(float4*)&zp[2] = make_float4(lv.z, fv.z, lv.w, fv.w);
        return;
    }

    __shared__ float sl[38][40];   // halo input, stride 40 -> <=2-way banks
    __shared__ float sf[38][40];
    __shared__ float hl[38][33];   // horizontal-blurred intermediate
    __shared__ float hf[38][33];

    // halo load: rows [by-3, by+35), cols [bx-3, bx+35), zero-pad OOB
    for (int i = tid; i < 38 * 38; i += 256) {
        int r = i / 38, cc = i - r * 38;
        int gy = by + r - 3, gx = bx + cc - 3;
        bool ok = (gy >= 0 && gy < SS && gx >= 0 && gx < SS);
        size_t off = ((size_t)gy << 10) + gx;
        sl[r][cc] = ok ? L[off] : 0.0f;
        sf[r][cc] = ok ? F[off] : 0.0f;
    }
    __syncthreads();

    // Gaussian weights (sigma=1, ks=7)
    double e1 = exp(-0.5), e2 = exp(-2.0), e3 = exp(-4.5);
    double sm = 1.0 + 2.0 * (e1 + e2 + e3);
    float w[7] = { (float)(e3 / sm), (float)(e2 / sm), (float)(e1 / sm),
                   (float)(1.0 / sm),
                   (float)(e1 / sm), (float)(e2 / sm), (float)(e3 / sm) };

    // stage 1: horizontal blur. 38 rows x 8 groups of 4 cols = 304 tasks
    for (int t = tid; t < 304; t += 256) {
        int r = t >> 3, g = (t & 7) * 4;
        float a[10], b[10];
        #pragma unroll
        for (int j = 0; j < 10; ++j) { a[j] = sl[r][g + j]; b[j] = sf[r][g + j]; }
        #pragma unroll
        for (int k = 0; k < 4; ++k) {
            float ol = 0.0f, of = 0.0f;
            #pragma unroll
            for (int j = 0; j < 7; ++j) { ol += w[j] * a[k + j]; of += w[j] * b[k + j]; }
            hl[r][g + k] = ol;
            hf[r][g + k] = of;
        }
    }
    __syncthreads();

    // stage 2: vertical blur + alpha blend + packed store.
    {
        int col = tid & 31, rg = (tid >> 5) * 4;
        int x = bx + col;
        float vl[10], vf[10];
        #pragma unroll
        for (int j = 0; j < 10; ++j) { vl[j] = hl[rg + j][col]; vf[j] = hf[rg + j][col]; }
        int gx = (x < BWD) ? x : ((SS - 1 - x) < BWD ? (SS - 1 - x) : -1);
        #pragma unroll
        for (int k = 0; k < 4; ++k) {
            int oy = rg + k, y = by + oy;
            float bl = 0.0f, bf = 0.0f;
            #pragma unroll
            for (int j = 0; j < 7; ++j) { bl += w[j] * vl[k + j]; bf += w[j] * vf[k + j]; }
            int gy = (y < BWD) ? y : ((SS - 1 - y) < BWD ? (SS - 1 - y) : -1);
            int m = gy > gx ? gy : gx;
            float a = (m >= 0) ? (float)m / (float)BWD : 1.0f;
            float cl = sl[oy + 3][col + 3], cf = sf[oy + 3][col + 3];
            Zc[((size_t)y << 10) + x] =
                make_float2(a * cl + (1.0f - a) * bl, a * cf + (1.0f - a) * bf);
        }
    }
}

// ---------------------------------------------------------------------------
// 1024-point Stockham RADIX-4 FFT pieces. 256 threads, 5 stages.
// lut[k] = exp(DIRSIGN * 2*pi*i*k/1024), k in [0,768).
// fft_stages: caller fills bufA + lut then __syncthreads(); result in bufB.
// ---------------------------------------------------------------------------
template <int DIRSIGN>
__device__ __forceinline__ void fft_fill_lut(float2* lut, int tid) {
    for (int i = tid; i < 768; i += 256) {
        float ang = (float)DIRSIGN * 6.28318530717958647692f * (float)i *
                    (1.0f / 1024.0f);
        float sv, cv;
        sincosf(ang, &sv, &cv);
        lut[i] = make_float2(cv, sv);
    }
}

template <int DIRSIGN>
__device__ __forceinline__ void fft_stages(float2* bufA, float2* bufB,
                                           const float2* lut, int tid) {
    float2* src = bufA;
    float2* dst = bufB;
    #pragma unroll
    for (int t = 0; t < 5; ++t) {
        int s = 1 << (2 * t);
        int k = tid & ~(s - 1);           // p*s, twiddle index
        float2 a = src[tid];
        float2 b = src[tid + 256];
        float2 c = src[tid + 512];
        float2 d = src[tid + 768];
        float2 apc = make_float2(a.x + c.x, a.y + c.y);
        float2 amc = make_float2(a.x - c.x, a.y - c.y);
        float2 bpd = make_float2(b.x + d.x, b.y + d.y);
        float2 jb  = make_float2(-(b.y - d.y), b.x - d.x);   // i*(b-d)
        float2 t1, t3;
        if (DIRSIGN == -1) {
            t1 = make_float2(amc.x - jb.x, amc.y - jb.y);
            t3 = make_float2(amc.x + jb.x, amc.y + jb.y);
        } else {
            t1 = make_float2(amc.x + jb.x, amc.y + jb.y);
            t3 = make_float2(amc.x - jb.x, amc.y - jb.y);
        }
        float2 w1 = lut[k], w2 = lut[2 * k], w3 = lut[3 * k];
        int base = tid + 3 * k;           // q + 4*s*p
        dst[base]         = make_float2(apc.x + bpd.x, apc.y + bpd.y);
        dst[base + s]     = cmul(t1, w1);
        dst[base + 2 * s] = cmul(make_float2(apc.x - bpd.x, apc.y - bpd.y), w2);
        dst[base + 3 * s] = cmul(t3, w3);
        __syncthreads();
        float2* tmp = src; src = dst; dst = tmp;
    }
    // 5 stages (odd) -> final result in bufB
}

template <int DIRSIGN>
__global__ __launch_bounds__(256) void fft_rows_kernel(float2* __restrict__ data,
                                                       float scale) {
    __shared__ float2 bufA[1024];
    __shared__ float2 bufB[1024];
    __shared__ float2 lut[768];
    int tid = threadIdx.x;
    size_t base = (size_t)blockIdx.x << 10;
    const float4* g = (const float4*)(data + base);
    #pragma unroll
    for (int h = 0; h < 2; ++h) {
        float4 v = g[tid + (h << 8)];
        int k = (tid + (h << 8)) << 1;
        bufA[k]     = make_float2(v.x, v.y);
        bufA[k + 1] = make_float2(v.z, v.w);
    }
    fft_fill_lut<DIRSIGN>(lut, tid);
    __syncthreads();
    fft_stages<DIRSIGN>(bufA, bufB, lut, tid);
    float4* go = (float4*)(data + base);
    #pragma unroll
    for (int h = 0; h < 2; ++h) {
        int k = (tid + (h << 8)) << 1;
        float2 v0 = bufB[k], v1 = bufB[k + 1];
        go[tid + (h << 8)] = make_float4(v0.x * scale, v0.y * scale,
                                         v1.x * scale, v1.y * scale);
    }
}

// ---------------------------------------------------------------------------
// Fused second forward FFT pass + Wiener. One block owns a conjugate row
// pair (u, 1024-u) for a channel pair p: 4 sequential FFTs into LDS result
// slots (slot = rowIdx*2 + ch), then Wiener entirely from LDS, write W.
// Block i=0 handles the self-paired rows {0, 512}.
// ---------------------------------------------------------------------------
__global__ __launch_bounds__(256) void fft2_wiener_kernel(
        const float2* __restrict__ Z, float2* __restrict__ W) {
    __shared__ float2 resbuf[4][1024];
    __shared__ float2 scratch[1024];
    __shared__ float2 lut[768];
    int tid = threadIdx.x;
    int p = blockIdx.x >> 9;          // channel pair 0..3
    int i = blockIdx.x & 511;
    int rows[2];
    rows[0] = (i == 0) ? 0 : i;
    rows[1] = (i == 0) ? 512 : 1024 - i;
    bool selfp = (i == 0);

    fft_fill_lut<-1>(lut, tid);

    // prefetch combo 0 (row0, ch0)
    const float4* g = (const float4*)(Z + (((size_t)(2 * p) << 20) +
                                           ((size_t)rows[0] << 10)));
    float4 ra = g[tid], rb = g[tid + 256];
    #pragma unroll
    for (int combo = 0; combo < 4; ++combo) {
        int k0 = tid << 1, k1 = (tid + 256) << 1;
        scratch[k0]     = make_float2(ra.x, ra.y);
        scratch[k0 + 1] = make_float2(ra.z, ra.w);
        scratch[k1]     = make_float2(rb.x, rb.y);
        scratch[k1 + 1] = make_float2(rb.z, rb.w);
        if (combo < 3) {
            int nr = (combo + 1) >> 1, nc = (combo + 1) & 1;
            const float4* gn = (const float4*)(Z +
                (((size_t)(2 * p + nc) << 20) + ((size_t)rows[nr] << 10)));
            ra = gn[tid];
            rb = gn[tid + 256];
        }
        __syncthreads();   // scratch (+ lut on first iter) visible
        fft_stages<-1>(scratch, resbuf[combo], lut, tid);
        // trailing syncthreads inside fft_stages: resbuf[combo] visible,
        // scratch free for refill
    }

    // Wiener phase: v = tid + 256*j (stride-1 lanes -> conflict-free LDS)
    const float TPN = 6.28318530717958647692f / 1024.0f;
    #pragma unroll
    for (int o = 0; o < 2; ++o) {
        int u = rows[o];
        int po = selfp ? o : (1 - o);      // partner row's slot base
        float cu = cosf(TPN * (float)u);
        float c2u = 2.0f * cu * cu - 1.0f;
        float hu = 2.0f + 2.0f * cu;
        float2* Wrow = W + (((size_t)p << 20) + ((size_t)u << 10));
        #pragma unroll
        for (int j = 0; j < 4; ++j) {
            int v = tid + (j << 8);
            int vn = (1024 - v) & 1023;
            float cv = cosf(TPN * (float)v);
            float c2v = 2.0f * cv * cv - 1.0f;
            float hv = 2.0f + 2.0f * cv;
            float grad = (2.0f - 2.0f * c2v) * hu * hu +
                         (2.0f - 2.0f * c2u) * hv * hv;
            float regs = 5.0f + 5.0f * grad;
            float G0x, G0y, G1x, G1y;
            #pragma unroll
            for (int c = 0; c < 2; ++c) {
                float2 a = resbuf[o * 2 + c][v];
                float2 b = resbuf[po * 2 + c][vn];
                float Lx = 0.5f * (a.x + b.x), Ly = 0.5f * (a.y - b.y);
                float Fx = 0.5f * (a.y + b.y), Fy = -0.5f * (a.x - b.x);
                float inv = 1.0f / (Fx * Fx + Fy * Fy + regs);
                float nx = (Fx * Lx + Fy * Ly) * inv;   // conj(F)*L
                float ny = (Fx * Ly - Fy * Lx) * inv;
                if (c == 0) { G0x = nx; G0y = ny; } else { G1x = nx; G1y = ny; }
            }
            Wrow[v] = make_float2(G0x - G1y, G0y + G1x);
        }
    }
}

// ---------------------------------------------------------------------------
// Final inverse pass: FFT over rows, fused 1/N scale + fftshift + threshold +
// split into two real psf planes + per-channel argmax (encoded atomicMax).
// ---------------------------------------------------------------------------
__global__ __launch_bounds__(256) void ifft_final_kernel(
        const float2* __restrict__ Wd, float* __restrict__ psf,
        ull* __restrict__ am) {
    __shared__ float2 bufA[1024];
    __shared__ float2 bufB[1024];
    __shared__ float2 lut[768];
    __shared__ ull red[256];
    int tid = threadIdx.x;
    size_t base = (size_t)blockIdx.x << 10;
    const float4* g = (const float4*)(Wd + base);
    #pragma unroll
    for (int h = 0; h < 2; ++h) {
        float4 v = g[tid + (h << 8)];
        int k = (tid + (h << 8)) << 1;
        bufA[k]     = make_float2(v.x, v.y);
        bufA[k + 1] = make_float2(v.z, v.w);
    }
    fft_fill_lut<1>(lut, tid);
    __syncthreads();
    fft_stages<1>(bufA, bufB, lut, tid);
    int p = blockIdx.x >> 10;
    int y = blockIdx.x & 1023;
    int oy = (y + 512) & 1023;
    float* p0 = psf + (((size_t)(2 * p) << 20) + ((size_t)oy << 10));
    float* p1 = p0 + (1u << 20);
    const float sc = 1.0f / 1024.0f;
    ull e0 = 0, e1 = 0;
    for (int k = tid; k < 1024; k += 256) {
        float2 v = bufB[k];
        float re = v.x * sc; re = (re < THRESH) ? 0.0f : re;
        float im = v.y * sc; im = (im < THRESH) ? 0.0f : im;
        int ox = (k + 512) & 1023;
        p0[ox] = re;
        p1[ox] = im;
        unsigned int idx = ((unsigned int)oy << 10) | (unsigned int)ox;
        ull c0 = ((ull)__float_as_uint(re) << 32) | (ull)(0xFFFFFFFFu - idx);
        ull c1 = ((ull)__float_as_uint(im) << 32) | (ull)(0xFFFFFFFFu - idx);
        e0 = c0 > e0 ? c0 : e0;
        e1 = c1 > e1 ? c1 : e1;
    }
    red[tid] = e0;
    __syncthreads();
    for (int s2 = 128; s2 > 0; s2 >>= 1) {
        if (tid < s2) { ull a = red[tid], b = red[tid + s2]; red[tid] = a > b ? a : b; }
        __syncthreads();
    }
    if (tid == 0) atomicMax(&am[2 * p], red[0]);
    __syncthreads();
    red[tid] = e1;
    __syncthreads();
    for (int s2 = 128; s2 > 0; s2 >>= 1) {
        if (tid < s2) { ull a = red[tid], b = red[tid + s2]; red[tid] = a > b ? a : b; }
        __syncthreads();
    }
    if (tid == 0) atomicMax(&am[2 * p + 1], red[0]);
}

// ---------------------------------------------------------------------------
// In-place square transpose, 32x32 tile pairs, per plane (grid.y = plane)
// ---------------------------------------------------------------------------
__global__ __launch_bounds__(256) void transpose_kernel(float2* __restrict__ A) {
    __shared__ float2 ta[32][33];
    __shared__ float2 tb[32][33];
    float2* P = A + ((size_t)blockIdx.y << 20);
    int r = blockIdx.x, bi = 0;
    while (r >= 32 - bi) { r -= 32 - bi; ++bi; }
    int bj = bi + r;
    int tx = threadIdx.x & 31, ty = threadIdx.x >> 5;
    for (int yy = ty; yy < 32; yy += 8) {
        ta[yy][tx] = P[(size_t)(bi * 32 + yy) * SS + bj * 32 + tx];
        tb[yy][tx] = P[(size_t)(bj * 32 + yy) * SS + bi * 32 + tx];
    }
    __syncthreads();
    for (int yy = ty; yy < 32; yy += 8) {
        P[(size_t)(bi * 32 + yy) * SS + bj * 32 + tx] = tb[tx][yy];
        P[(size_t)(bj * 32 + yy) * SS + bi * 32 + tx] = ta[tx][yy];
    }
}

// ---------------------------------------------------------------------------
__global__ void argmax_init_kernel(ull* am) {
    if (threadIdx.x < NC) am[threadIdx.x] = 0ull;
}

// ---------------------------------------------------------------------------
// Crop 41x41 around argmax (dynamic_slice clamp semantics) + normalize
// ---------------------------------------------------------------------------
__global__ __launch_bounds__(256) void crop_kernel(
        const float* __restrict__ psf, const ull* __restrict__ am,
        float* __restrict__ out) {
    int c = blockIdx.x;
    ull e = am[c];
    unsigned int bidx = 0xFFFFFFFFu - (unsigned int)(e & 0xFFFFFFFFull);
    int row = (int)(bidx >> 10), col = (int)(bidx & 1023);
    int r0 = row - 20; if (r0 < 0) r0 = 0; if (r0 > SS - 41) r0 = SS - 41;
    int c0 = col - 20; if (c0 < 0) c0 = 0; if (c0 > SS - 41) c0 = SS - 41;
    const float* p = psf + ((size_t)c << 20);
    float local = 0.0f;
    for (int i = threadIdx.x; i < 1681; i += 256) {
        int rr = i / 41, cc = i - rr * 41;
        local += p[(size_t)(r0 + rr) * SS + c0 + cc];
    }
    __shared__ float red[256];
    red[threadIdx.x] = local;
    __syncthreads();
    for (int s2 = 128; s2 > 0; s2 >>= 1) {
        if (threadIdx.x < s2) red[threadIdx.x] += red[threadIdx.x + s2];
        __syncthreads();
    }
    float inv = 1.0f / red[0];
    for (int i = threadIdx.x; i < 1681; i += 256) {
        int rr = i / 41, cc = i - rr * 41;
        out[c * 1681 + i] = p[(size_t)(r0 + rr) * SS + c0 + cc] * inv;
    }
}

// ---------------------------------------------------------------------------
extern "C" void kernel_launch(void* const* d_in, const int* in_sizes, int n_in,
                              void* d_out, int out_size, void* d_ws,
                              size_t ws_size, hipStream_t stream) {
    const float* lms = (const float*)d_in[0];
    const float* fuse = (const float*)d_in[1];
    char* ws = (char*)d_ws;
    float2* Zf = (float2*)ws;                                   // 64 MB: 8 planes
    float2* Wb = (float2*)(ws + ((size_t)64 << 20));            // 32 MB: 4 planes
    float* psf = (float*)ws;                                    // 32 MB, reuses Zf
    ull* am = (ull*)(ws + ((size_t)33 << 20));                  // in dead Zf region
    float* outp = (float*)d_out;

    // 1. blur + alpha blend + pack
    blur_pack_kernel<<<dim3(32, 32, 8), 256, 0, stream>>>(lms, fuse, Zf);
    // 2. forward FFT2: rows, transpose, then fused col-FFT + Wiener -> Wb
    fft_rows_kernel<-1><<<8192, 256, 0, stream>>>(Zf, 1.0f);
    transpose_kernel<<<dim3(528, 8), 256, 0, stream>>>(Zf);
    fft2_wiener_kernel<<<2048, 256, 0, stream>>>(Zf, Wb);
    // am lives at ws+33MB inside the Zf region: init only AFTER Zf's last
    // reader (fft2_wiener) — earlier placement gets clobbered by blur/fft.
    argmax_init_kernel<<<1, 64, 0, stream>>>(am);
    // 3. inverse FFT2 with fused shift/threshold/split/argmax on last pass
    fft_rows_kernel<1><<<4096, 256, 0, stream>>>(Wb, 1.0f / 1024.0f);
    transpose_kernel<<<dim3(528, 4), 256, 0, stream>>>(Wb);
    ifft_final_kernel<<<4096, 256, 0, stream>>>(Wb, psf, am);
    // 4. crop/normalize
    crop_kernel<<<8, 256, 0, stream>>>(psf, am, outp);
}

// Round 6
// 258.883 us; speedup vs baseline: 1.3042x; 1.3042x over previous
//
#include <hip/hip_runtime.h>
#include <math.h>

#define SS 1024
#define NC 8
#define BWD 170
#define THRESH 1e-4f

typedef unsigned long long ull;

__device__ __forceinline__ float2 cmul(float2 a, float2 b) {
    return make_float2(a.x * b.x - a.y * b.y, a.x * b.y + a.y * b.x);
}

// ---------------------------------------------------------------------------
// Blur + alpha blend + pack. Two-stage separable filter, 32x32 output tile,
// interior (alpha==1) fast path. Z[c][y][x] = lms_e + i * fuse_e
// ---------------------------------------------------------------------------
__global__ __launch_bounds__(256) void blur_pack_kernel(
        const float* __restrict__ lms, const float* __restrict__ fuse,
        float2* __restrict__ Z) {
    int c = blockIdx.z;
    int bx = blockIdx.x * 32, by = blockIdx.y * 32;
    int tid = threadIdx.x;
    const float* L = lms + ((size_t)c << 20);
    const float* F = fuse + ((size_t)c << 20);
    float2* Zc = Z + ((size_t)c << 20);

    // alpha==1 iff row,col in [BWD, SS-1-BWD]; block-uniform fast path
    bool fast = (bx >= BWD) && (bx + 31 <= SS - 1 - BWD) &&
                (by >= BWD) && (by + 31 <= SS - 1 - BWD);
    if (fast) {
        int r = tid >> 3, g = (tid & 7) * 4;
        int y = by + r, x = bx + g;
        float4 lv = *(const float4*)&L[((size_t)y << 10) + x];
        float4 fv = *(const float4*)&F[((size_t)y << 10) + x];
        float2* zp = &Zc[((size_t)y << 10) + x];
        *(float4*)&zp[0] = make_float4(lv.x, fv.x, lv.y, fv.y);
        *(float4*)&zp[2] = make_float4(lv.z, fv.z, lv.w, fv.w);
        return;
    }

    __shared__ float sl[38][40];   // halo input, stride 40 -> <=2-way banks
    __shared__ float sf[38][40];
    __shared__ float hl[38][33];   // horizontal-blurred intermediate
    __shared__ float hf[38][33];

    // halo load: rows [by-3, by+35), cols [bx-3, bx+35), zero-pad OOB
    for (int i = tid; i < 38 * 38; i += 256) {
        int r = i / 38, cc = i - r * 38;
        int gy = by + r - 3, gx = bx + cc - 3;
        bool ok = (gy >= 0 && gy < SS && gx >= 0 && gx < SS);
        size_t off = ((size_t)gy << 10) + gx;
        sl[r][cc] = ok ? L[off] : 0.0f;
        sf[r][cc] = ok ? F[off] : 0.0f;
    }
    __syncthreads();

    // Gaussian weights (sigma=1, ks=7)
    double e1 = exp(-0.5), e2 = exp(-2.0), e3 = exp(-4.5);
    double sm = 1.0 + 2.0 * (e1 + e2 + e3);
    float w[7] = { (float)(e3 / sm), (float)(e2 / sm), (float)(e1 / sm),
                   (float)(1.0 / sm),
                   (float)(e1 / sm), (float)(e2 / sm), (float)(e3 / sm) };

    // stage 1: horizontal blur. 38 rows x 8 groups of 4 cols = 304 tasks
    for (int t = tid; t < 304; t += 256) {
        int r = t >> 3, g = (t & 7) * 4;
        float a[10], b[10];
        #pragma unroll
        for (int j = 0; j < 10; ++j) { a[j] = sl[r][g + j]; b[j] = sf[r][g + j]; }
        #pragma unroll
        for (int k = 0; k < 4; ++k) {
            float ol = 0.0f, of = 0.0f;
            #pragma unroll
            for (int j = 0; j < 7; ++j) { ol += w[j] * a[k + j]; of += w[j] * b[k + j]; }
            hl[r][g + k] = ol;
            hf[r][g + k] = of;
        }
    }
    __syncthreads();

    // stage 2: vertical blur + alpha blend + packed store.
    {
        int col = tid & 31, rg = (tid >> 5) * 4;
        int x = bx + col;
        float vl[10], vf[10];
        #pragma unroll
        for (int j = 0; j < 10; ++j) { vl[j] = hl[rg + j][col]; vf[j] = hf[rg + j][col]; }
        int gx = (x < BWD) ? x : ((SS - 1 - x) < BWD ? (SS - 1 - x) : -1);
        #pragma unroll
        for (int k = 0; k < 4; ++k) {
            int oy = rg + k, y = by + oy;
            float bl = 0.0f, bf = 0.0f;
            #pragma unroll
            for (int j = 0; j < 7; ++j) { bl += w[j] * vl[k + j]; bf += w[j] * vf[k + j]; }
            int gy = (y < BWD) ? y : ((SS - 1 - y) < BWD ? (SS - 1 - y) : -1);
            int m = gy > gx ? gy : gx;
            float a = (m >= 0) ? (float)m / (float)BWD : 1.0f;
            float cl = sl[oy + 3][col + 3], cf = sf[oy + 3][col + 3];
            Zc[((size_t)y << 10) + x] =
                make_float2(a * cl + (1.0f - a) * bl, a * cf + (1.0f - a) * bf);
        }
    }
}

// ---------------------------------------------------------------------------
// 1024-point Stockham RADIX-4 FFT pieces. 256 threads, 5 stages.
// lut[k] = exp(DIRSIGN * 2*pi*i*k/1024), k in [0,768).
// fft_stages: caller fills bufA + lut then __syncthreads(); result in bufB.
// ---------------------------------------------------------------------------
template <int DIRSIGN>
__device__ __forceinline__ void fft_fill_lut(float2* lut, int tid) {
    for (int i = tid; i < 768; i += 256) {
        float ang = (float)DIRSIGN * 6.28318530717958647692f * (float)i *
                    (1.0f / 1024.0f);
        float sv, cv;
        sincosf(ang, &sv, &cv);
        lut[i] = make_float2(cv, sv);
    }
}

template <int DIRSIGN>
__device__ __forceinline__ void fft_stages(float2* bufA, float2* bufB,
                                           const float2* lut, int tid) {
    float2* src = bufA;
    float2* dst = bufB;
    #pragma unroll
    for (int t = 0; t < 5; ++t) {
        int s = 1 << (2 * t);
        int k = tid & ~(s - 1);           // p*s, twiddle index
        float2 a = src[tid];
        float2 b = src[tid + 256];
        float2 c = src[tid + 512];
        float2 d = src[tid + 768];
        float2 apc = make_float2(a.x + c.x, a.y + c.y);
        float2 amc = make_float2(a.x - c.x, a.y - c.y);
        float2 bpd = make_float2(b.x + d.x, b.y + d.y);
        float2 jb  = make_float2(-(b.y - d.y), b.x - d.x);   // i*(b-d)
        float2 t1, t3;
        if (DIRSIGN == -1) {
            t1 = make_float2(amc.x - jb.x, amc.y - jb.y);
            t3 = make_float2(amc.x + jb.x, amc.y + jb.y);
        } else {
            t1 = make_float2(amc.x + jb.x, amc.y + jb.y);
            t3 = make_float2(amc.x - jb.x, amc.y - jb.y);
        }
        float2 w1 = lut[k], w2 = lut[2 * k], w3 = lut[3 * k];
        int base = tid + 3 * k;           // q + 4*s*p
        dst[base]         = make_float2(apc.x + bpd.x, apc.y + bpd.y);
        dst[base + s]     = cmul(t1, w1);
        dst[base + 2 * s] = cmul(make_float2(apc.x - bpd.x, apc.y - bpd.y), w2);
        dst[base + 3 * s] = cmul(t3, w3);
        __syncthreads();
        float2* tmp = src; src = dst; dst = tmp;
    }
    // 5 stages (odd) -> final result in bufB
}

template <int DIRSIGN>
__global__ __launch_bounds__(256) void fft_rows_kernel(float2* __restrict__ data,
                                                       float scale) {
    __shared__ float2 bufA[1024];
    __shared__ float2 bufB[1024];
    __shared__ float2 lut[768];
    int tid = threadIdx.x;
    size_t base = (size_t)blockIdx.x << 10;
    const float4* g = (const float4*)(data + base);
    #pragma unroll
    for (int h = 0; h < 2; ++h) {
        float4 v = g[tid + (h << 8)];
        int k = (tid + (h << 8)) << 1;
        bufA[k]     = make_float2(v.x, v.y);
        bufA[k + 1] = make_float2(v.z, v.w);
    }
    fft_fill_lut<DIRSIGN>(lut, tid);
    __syncthreads();
    fft_stages<DIRSIGN>(bufA, bufB, lut, tid);
    float4* go = (float4*)(data + base);
    #pragma unroll
    for (int h = 0; h < 2; ++h) {
        int k = (tid + (h << 8)) << 1;
        float2 v0 = bufB[k], v1 = bufB[k + 1];
        go[tid + (h << 8)] = make_float4(v0.x * scale, v0.y * scale,
                                         v1.x * scale, v1.y * scale);
    }
}

// ---------------------------------------------------------------------------
// Fused second forward FFT pass + Wiener. One block owns a conjugate row
// pair (u, 1024-u) for a channel pair p: 4 sequential FFTs into LDS result
// slots (slot = rowIdx*2 + ch), then Wiener entirely from LDS, write W.
// Block i=0 handles the self-paired rows {0, 512}.
// ---------------------------------------------------------------------------
__global__ __launch_bounds__(256) void fft2_wiener_kernel(
        const float2* __restrict__ Z, float2* __restrict__ W) {
    __shared__ float2 resbuf[4][1024];
    __shared__ float2 scratch[1024];
    __shared__ float2 lut[768];
    int tid = threadIdx.x;
    int p = blockIdx.x >> 9;          // channel pair 0..3
    int i = blockIdx.x & 511;
    int rows[2];
    rows[0] = (i == 0) ? 0 : i;
    rows[1] = (i == 0) ? 512 : 1024 - i;
    bool selfp = (i == 0);

    fft_fill_lut<-1>(lut, tid);

    // prefetch combo 0 (row0, ch0)
    const float4* g = (const float4*)(Z + (((size_t)(2 * p) << 20) +
                                           ((size_t)rows[0] << 10)));
    float4 ra = g[tid], rb = g[tid + 256];
    #pragma unroll
    for (int combo = 0; combo < 4; ++combo) {
        int k0 = tid << 1, k1 = (tid + 256) << 1;
        scratch[k0]     = make_float2(ra.x, ra.y);
        scratch[k0 + 1] = make_float2(ra.z, ra.w);
        scratch[k1]     = make_float2(rb.x, rb.y);
        scratch[k1 + 1] = make_float2(rb.z, rb.w);
        if (combo < 3) {
            int nr = (combo + 1) >> 1, nc = (combo + 1) & 1;
            const float4* gn = (const float4*)(Z +
                (((size_t)(2 * p + nc) << 20) + ((size_t)rows[nr] << 10)));
            ra = gn[tid];
            rb = gn[tid + 256];
        }
        __syncthreads();   // scratch (+ lut on first iter) visible
        fft_stages<-1>(scratch, resbuf[combo], lut, tid);
        // trailing syncthreads inside fft_stages: resbuf[combo] visible,
        // scratch free for refill
    }

    // Wiener phase: v = tid + 256*j (stride-1 lanes -> conflict-free LDS)
    const float TPN = 6.28318530717958647692f / 1024.0f;
    #pragma unroll
    for (int o = 0; o < 2; ++o) {
        int u = rows[o];
        int po = selfp ? o : (1 - o);      // partner row's slot base
        float cu = cosf(TPN * (float)u);
        float c2u = 2.0f * cu * cu - 1.0f;
        float hu = 2.0f + 2.0f * cu;
        float2* Wrow = W + (((size_t)p << 20) + ((size_t)u << 10));
        #pragma unroll
        for (int j = 0; j < 4; ++j) {
            int v = tid + (j << 8);
            int vn = (1024 - v) & 1023;
            float cv = cosf(TPN * (float)v);
            float c2v = 2.0f * cv * cv - 1.0f;
            float hv = 2.0f + 2.0f * cv;
            float grad = (2.0f - 2.0f * c2v) * hu * hu +
                         (2.0f - 2.0f * c2u) * hv * hv;
            float regs = 5.0f + 5.0f * grad;
            float G0x, G0y, G1x, G1y;
            #pragma unroll
            for (int c = 0; c < 2; ++c) {
                float2 a = resbuf[o * 2 + c][v];
                float2 b = resbuf[po * 2 + c][vn];
                float Lx = 0.5f * (a.x + b.x), Ly = 0.5f * (a.y - b.y);
                float Fx = 0.5f * (a.y + b.y), Fy = -0.5f * (a.x - b.x);
                float inv = 1.0f / (Fx * Fx + Fy * Fy + regs);
                float nx = (Fx * Lx + Fy * Ly) * inv;   // conj(F)*L
                float ny = (Fx * Ly - Fy * Lx) * inv;
                if (c == 0) { G0x = nx; G0y = ny; } else { G1x = nx; G1y = ny; }
            }
            Wrow[v] = make_float2(G0x - G1y, G0y + G1x);
        }
    }
}

// ---------------------------------------------------------------------------
// Final inverse pass: FFT over rows, fused 1/N scale + fftshift + threshold +
// split into two real psf planes + per-block argmax written to a PRIVATE slot
// (bm[channel*1024 + row]) — no hot atomics (R5 lesson: 1024 same-address
// device atomicMax serialized ~85us at the coherence point).
// ---------------------------------------------------------------------------
__global__ __launch_bounds__(256) void ifft_final_kernel(
        const float2* __restrict__ Wd, float* __restrict__ psf,
        ull* __restrict__ bm) {
    __shared__ float2 bufA[1024];
    __shared__ float2 bufB[1024];
    __shared__ float2 lut[768];
    __shared__ ull red[256];
    int tid = threadIdx.x;
    size_t base = (size_t)blockIdx.x << 10;
    const float4* g = (const float4*)(Wd + base);
    #pragma unroll
    for (int h = 0; h < 2; ++h) {
        float4 v = g[tid + (h << 8)];
        int k = (tid + (h << 8)) << 1;
        bufA[k]     = make_float2(v.x, v.y);
        bufA[k + 1] = make_float2(v.z, v.w);
    }
    fft_fill_lut<1>(lut, tid);
    __syncthreads();
    fft_stages<1>(bufA, bufB, lut, tid);
    int p = blockIdx.x >> 10;
    int y = blockIdx.x & 1023;
    int oy = (y + 512) & 1023;
    float* p0 = psf + (((size_t)(2 * p) << 20) + ((size_t)oy << 10));
    float* p1 = p0 + (1u << 20);
    const float sc = 1.0f / 1024.0f;
    ull e0 = 0, e1 = 0;
    for (int k = tid; k < 1024; k += 256) {
        float2 v = bufB[k];
        float re = v.x * sc; re = (re < THRESH) ? 0.0f : re;
        float im = v.y * sc; im = (im < THRESH) ? 0.0f : im;
        int ox = (k + 512) & 1023;
        p0[ox] = re;
        p1[ox] = im;
        unsigned int idx = ((unsigned int)oy << 10) | (unsigned int)ox;
        ull c0 = ((ull)__float_as_uint(re) << 32) | (ull)(0xFFFFFFFFu - idx);
        ull c1 = ((ull)__float_as_uint(im) << 32) | (ull)(0xFFFFFFFFu - idx);
        e0 = c0 > e0 ? c0 : e0;
        e1 = c1 > e1 ? c1 : e1;
    }
    red[tid] = e0;
    __syncthreads();
    for (int s2 = 128; s2 > 0; s2 >>= 1) {
        if (tid < s2) { ull a = red[tid], b = red[tid + s2]; red[tid] = a > b ? a : b; }
        __syncthreads();
    }
    if (tid == 0) bm[((size_t)(2 * p) << 10) + y] = red[0];
    __syncthreads();
    red[tid] = e1;
    __syncthreads();
    for (int s2 = 128; s2 > 0; s2 >>= 1) {
        if (tid < s2) { ull a = red[tid], b = red[tid + s2]; red[tid] = a > b ? a : b; }
        __syncthreads();
    }
    if (tid == 0) bm[((size_t)(2 * p + 1) << 10) + y] = red[0];
}

// ---------------------------------------------------------------------------
// In-place square transpose, 32x32 tile pairs, per plane (grid.y = plane)
// ---------------------------------------------------------------------------
__global__ __launch_bounds__(256) void transpose_kernel(float2* __restrict__ A) {
    __shared__ float2 ta[32][33];
    __shared__ float2 tb[32][33];
    float2* P = A + ((size_t)blockIdx.y << 20);
    int r = blockIdx.x, bi = 0;
    while (r >= 32 - bi) { r -= 32 - bi; ++bi; }
    int bj = bi + r;
    int tx = threadIdx.x & 31, ty = threadIdx.x >> 5;
    for (int yy = ty; yy < 32; yy += 8) {
        ta[yy][tx] = P[(size_t)(bi * 32 + yy) * SS + bj * 32 + tx];
        tb[yy][tx] = P[(size_t)(bj * 32 + yy) * SS + bi * 32 + tx];
    }
    __syncthreads();
    for (int yy = ty; yy < 32; yy += 8) {
        P[(size_t)(bi * 32 + yy) * SS + bj * 32 + tx] = tb[tx][yy];
        P[(size_t)(bj * 32 + yy) * SS + bi * 32 + tx] = ta[tx][yy];
    }
}

// ---------------------------------------------------------------------------
// Per-channel argmax finish (reduce 1024 per-block maxima) + crop 41x41
// (dynamic_slice clamp semantics) + normalize. One block per channel.
// ---------------------------------------------------------------------------
__global__ __launch_bounds__(256) void crop_kernel(
        const float* __restrict__ psf, const ull* __restrict__ bm,
        float* __restrict__ out) {
    int c = blockIdx.x;
    __shared__ ull rmax[256];
    __shared__ float red[256];
    int tid = threadIdx.x;
    ull e = 0;
    for (int i = tid; i < 1024; i += 256) {
        ull v = bm[((size_t)c << 10) + i];
        e = v > e ? v : e;
    }
    rmax[tid] = e;
    __syncthreads();
    for (int s2 = 128; s2 > 0; s2 >>= 1) {
        if (tid < s2) { ull a = rmax[tid], b = rmax[tid + s2]; rmax[tid] = a > b ? a : b; }
        __syncthreads();
    }
    unsigned int bidx = 0xFFFFFFFFu - (unsigned int)(rmax[0] & 0xFFFFFFFFull);
    int row = (int)(bidx >> 10), col = (int)(bidx & 1023);
    int r0 = row - 20; if (r0 < 0) r0 = 0; if (r0 > SS - 41) r0 = SS - 41;
    int c0 = col - 20; if (c0 < 0) c0 = 0; if (c0 > SS - 41) c0 = SS - 41;
    const float* p = psf + ((size_t)c << 20);
    float local = 0.0f;
    for (int i = tid; i < 1681; i += 256) {
        int rr = i / 41, cc = i - rr * 41;
        local += p[(size_t)(r0 + rr) * SS + c0 + cc];
    }
    red[tid] = local;
    __syncthreads();
    for (int s2 = 128; s2 > 0; s2 >>= 1) {
        if (tid < s2) red[tid] += red[tid + s2];
        __syncthreads();
    }
    float inv = 1.0f / red[0];
    for (int i = tid; i < 1681; i += 256) {
        int rr = i / 41, cc = i - rr * 41;
        out[c * 1681 + i] = p[(size_t)(r0 + rr) * SS + c0 + cc] * inv;
    }
}

// ---------------------------------------------------------------------------
extern "C" void kernel_launch(void* const* d_in, const int* in_sizes, int n_in,
                              void* d_out, int out_size, void* d_ws,
                              size_t ws_size, hipStream_t stream) {
    const float* lms = (const float*)d_in[0];
    const float* fuse = (const float*)d_in[1];
    char* ws = (char*)d_ws;
    float2* Zf = (float2*)ws;                                   // 64 MB: 8 planes
    float2* Wb = (float2*)(ws + ((size_t)64 << 20));            // 32 MB: 4 planes
    float* psf = (float*)ws;                                    // 32 MB, reuses Zf
    ull* bm = (ull*)(ws + ((size_t)33 << 20));                  // 64 KB, dead Zf region
    float* outp = (float*)d_out;

    // 1. blur + alpha blend + pack
    blur_pack_kernel<<<dim3(32, 32, 8), 256, 0, stream>>>(lms, fuse, Zf);
    // 2. forward FFT2: rows, transpose, then fused col-FFT + Wiener -> Wb
    fft_rows_kernel<-1><<<8192, 256, 0, stream>>>(Zf, 1.0f);
    transpose_kernel<<<dim3(528, 8), 256, 0, stream>>>(Zf);
    fft2_wiener_kernel<<<2048, 256, 0, stream>>>(Zf, Wb);
    // 3. inverse FFT2 with fused shift/threshold/split/block-argmax
    fft_rows_kernel<1><<<4096, 256, 0, stream>>>(Wb, 1.0f / 1024.0f);
    transpose_kernel<<<dim3(528, 4), 256, 0, stream>>>(Wb);
    ifft_final_kernel<<<4096, 256, 0, stream>>>(Wb, psf, bm);
    // 4. argmax finish + crop/normalize
    crop_kernel<<<8, 256, 0, stream>>>(psf, bm, outp);
}

// Round 7
// 246.599 us; speedup vs baseline: 1.3691x; 1.0498x over previous
//
#include <hip/hip_runtime.h>
#include <math.h>

#define SS 1024
#define NC 8
#define BWD 170
#define THRESH 1e-4f

typedef unsigned long long ull;

__device__ __forceinline__ float2 cmul(float2 a, float2 b) {
    return make_float2(a.x * b.x - a.y * b.y, a.x * b.y + a.y * b.x);
}

// ---------------------------------------------------------------------------
// 1024-point Stockham RADIX-4 FFT pieces. 256 threads, 5 stages.
// lut[k] = exp(DIRSIGN * 2*pi*i*k/1024), k in [0,768).
// CONJ=true conjugates the twiddles at use (inverse FFT from a forward lut);
// pair it with DIRSIGN=+1 semantics in the butterfly.
// Caller fills bufA + lut then __syncthreads(); result lands in bufB.
// ---------------------------------------------------------------------------
template <int DIRSIGN>
__device__ __forceinline__ void fft_fill_lut(float2* lut, int tid) {
    for (int i = tid; i < 768; i += 256) {
        float ang = (float)DIRSIGN * 6.28318530717958647692f * (float)i *
                    (1.0f / 1024.0f);
        float sv, cv;
        sincosf(ang, &sv, &cv);
        lut[i] = make_float2(cv, sv);
    }
}

template <int DIRSIGN, bool CONJ>
__device__ __forceinline__ void fft_stages(float2* bufA, float2* bufB,
                                           const float2* lut, int tid) {
    float2* src = bufA;
    float2* dst = bufB;
    #pragma unroll
    for (int t = 0; t < 5; ++t) {
        int s = 1 << (2 * t);
        int k = tid & ~(s - 1);           // p*s, twiddle index
        float2 a = src[tid];
        float2 b = src[tid + 256];
        float2 c = src[tid + 512];
        float2 d = src[tid + 768];
        float2 apc = make_float2(a.x + c.x, a.y + c.y);
        float2 amc = make_float2(a.x - c.x, a.y - c.y);
        float2 bpd = make_float2(b.x + d.x, b.y + d.y);
        float2 jb  = make_float2(-(b.y - d.y), b.x - d.x);   // i*(b-d)
        float2 t1, t3;
        if (DIRSIGN == -1) {
            t1 = make_float2(amc.x - jb.x, amc.y - jb.y);
            t3 = make_float2(amc.x + jb.x, amc.y + jb.y);
        } else {
            t1 = make_float2(amc.x + jb.x, amc.y + jb.y);
            t3 = make_float2(amc.x - jb.x, amc.y - jb.y);
        }
        float2 w1 = lut[k], w2 = lut[2 * k], w3 = lut[3 * k];
        if (CONJ) { w1.y = -w1.y; w2.y = -w2.y; w3.y = -w3.y; }
        int base = tid + 3 * k;           // q + 4*s*p
        dst[base]         = make_float2(apc.x + bpd.x, apc.y + bpd.y);
        dst[base + s]     = cmul(t1, w1);
        dst[base + 2 * s] = cmul(make_float2(apc.x - bpd.x, apc.y - bpd.y), w2);
        dst[base + 3 * s] = cmul(t3, w3);
        __syncthreads();
        float2* tmp = src; src = dst; dst = tmp;
    }
    // 5 stages (odd) -> final result in bufB
}

// ---------------------------------------------------------------------------
// Fused blur + alpha blend + pack + forward row FFT. Block = (channel, row).
// V-blur in registers (7 float4 row loads; column halo V-blur is exactly 0
// because cols <0 / >=1024 are zero-padded), H-blur via one LDS row,
// alpha blend, pack Z = lms_e + i*fuse_e, 1024-pt FFT, write Zf[c][y][kx].
// Interior rows (alpha==1 for threads' cols): skip the 6 extra row loads.
// ---------------------------------------------------------------------------
__global__ __launch_bounds__(256) void blur_fft_kernel(
        const float* __restrict__ lms, const float* __restrict__ fuse,
        float2* __restrict__ Zf) {
    __shared__ float2 bufA[1024];      // FFT input
    __shared__ float smemB[2080];      // aliases: rowl/rowf, then FFT bufB
    __shared__ float2 lut[768];
    float2* bufB = (float2*)smemB;
    float* rowl = smemB;               // idx = col+3, cols -3..1026
    float* rowf = smemB + 1040;
    int tid = threadIdx.x;
    int c = blockIdx.x >> 10, y = blockIdx.x & 1023;
    const float* L = lms + ((size_t)c << 20);
    const float* F = fuse + ((size_t)c << 20);
    int x0 = tid << 2;

    // Gaussian weights (sigma=1, ks=7)
    double e1 = exp(-0.5), e2 = exp(-2.0), e3 = exp(-4.5);
    double sm = 1.0 + 2.0 * (e1 + e2 + e3);
    float w[7] = { (float)(e3 / sm), (float)(e2 / sm), (float)(e1 / sm),
                   (float)(1.0 / sm),
                   (float)(e1 / sm), (float)(e2 / sm), (float)(e3 / sm) };

    bool rowInt = (y >= BWD) && (y <= SS - 1 - BWD);
    // skipLoads threads: cols 180..843, all alpha==1, nobody reads their
    // rowl entries (H-blur readers are tid<=43 / >=212 reading cols
    // <=178 / >=845, written by tid<=44 / >=211).
    bool skipLoads = rowInt && (tid >= 45) && (tid <= 210);
    bool doH = !rowInt || (tid <= 43) || (tid >= 212);

    float4 cl, cf;
    if (skipLoads) {
        cl = *(const float4*)&L[((size_t)y << 10) + x0];
        cf = *(const float4*)&F[((size_t)y << 10) + x0];
    } else {
        float4 lv[7], fv[7];
        #pragma unroll
        for (int r = 0; r < 7; ++r) {
            int gy = y - 3 + r;
            if (gy >= 0 && gy < SS) {
                lv[r] = *(const float4*)&L[((size_t)gy << 10) + x0];
                fv[r] = *(const float4*)&F[((size_t)gy << 10) + x0];
            } else {
                lv[r] = make_float4(0.f, 0.f, 0.f, 0.f);
                fv[r] = make_float4(0.f, 0.f, 0.f, 0.f);
            }
        }
        cl = lv[3]; cf = fv[3];
        #pragma unroll
        for (int j = 0; j < 4; ++j) {
            float a = 0.f, b = 0.f;
            #pragma unroll
            for (int r = 0; r < 7; ++r) {
                a += w[r] * (&lv[r].x)[j];
                b += w[r] * (&fv[r].x)[j];
            }
            rowl[3 + x0 + j] = a;
            rowf[3 + x0 + j] = b;
        }
    }
    if (tid < 3) {
        rowl[tid] = 0.f; rowf[tid] = 0.f;
        rowl[1027 + tid] = 0.f; rowf[1027 + tid] = 0.f;
    }
    fft_fill_lut<-1>(lut, tid);
    __syncthreads();

    float bl[4] = {0.f, 0.f, 0.f, 0.f}, bf[4] = {0.f, 0.f, 0.f, 0.f};
    if (doH) {
        #pragma unroll
        for (int k = 0; k < 4; ++k) {
            float a = 0.f, b = 0.f;
            #pragma unroll
            for (int j = 0; j < 7; ++j) {
                a += w[j] * rowl[x0 + k + j];
                b += w[j] * rowf[x0 + k + j];
            }
            bl[k] = a; bf[k] = b;
        }
    }
    int gyv = (y < BWD) ? y : ((SS - 1 - y) < BWD ? (SS - 1 - y) : -1);
    #pragma unroll
    for (int k = 0; k < 4; ++k) {
        int x = x0 + k;
        int gx = (x < BWD) ? x : ((SS - 1 - x) < BWD ? (SS - 1 - x) : -1);
        int m = gyv > gx ? gyv : gx;
        float a = (m >= 0) ? (float)m / (float)BWD : 1.0f;
        bufA[x] = make_float2(a * (&cl.x)[k] + (1.0f - a) * bl[k],
                              a * (&cf.x)[k] + (1.0f - a) * bf[k]);
    }
    __syncthreads();   // bufA ready; rowl/rowf reads done -> bufB reusable
    fft_stages<-1, false>(bufA, bufB, lut, tid);
    float4* go = (float4*)(Zf + ((size_t)blockIdx.x << 10));
    #pragma unroll
    for (int h = 0; h < 2; ++h) {
        int k = (tid + (h << 8)) << 1;
        float2 v0 = bufB[k], v1 = bufB[k + 1];
        go[tid + (h << 8)] = make_float4(v0.x, v0.y, v1.x, v1.y);
    }
}

// ---------------------------------------------------------------------------
// Fused second forward FFT + Wiener + first inverse FFT (along ky).
// One block owns a conjugate row pair (u, 1024-u) for a channel pair p:
// 4 forward FFTs into LDS slots, Wiener to registers, then 2 inverse FFTs
// (conjugated twiddles) and write Wb[p][u][y] directly — the standalone
// inverse-rows pass is gone. Block i=0 handles self-paired rows {0, 512}.
// ---------------------------------------------------------------------------
__global__ __launch_bounds__(256) void fft2_wiener_kernel(
        const float2* __restrict__ Z, float2* __restrict__ Wb) {
    __shared__ float2 resbuf[4][1024];
    __shared__ float2 scratch[1024];
    __shared__ float2 lut[768];
    int tid = threadIdx.x;
    int p = blockIdx.x >> 9;          // channel pair 0..3
    int i = blockIdx.x & 511;
    int rows[2];
    rows[0] = (i == 0) ? 0 : i;
    rows[1] = (i == 0) ? 512 : 1024 - i;
    bool selfp = (i == 0);

    fft_fill_lut<-1>(lut, tid);

    // prefetch combo 0 (row0, ch0)
    const float4* g = (const float4*)(Z + (((size_t)(2 * p) << 20) +
                                           ((size_t)rows[0] << 10)));
    float4 ra = g[tid], rb = g[tid + 256];
    #pragma unroll
    for (int combo = 0; combo < 4; ++combo) {
        int k0 = tid << 1, k1 = (tid + 256) << 1;
        scratch[k0]     = make_float2(ra.x, ra.y);
        scratch[k0 + 1] = make_float2(ra.z, ra.w);
        scratch[k1]     = make_float2(rb.x, rb.y);
        scratch[k1 + 1] = make_float2(rb.z, rb.w);
        if (combo < 3) {
            int nr = (combo + 1) >> 1, nc = (combo + 1) & 1;
            const float4* gn = (const float4*)(Z +
                (((size_t)(2 * p + nc) << 20) + ((size_t)rows[nr] << 10)));
            ra = gn[tid];
            rb = gn[tid + 256];
        }
        __syncthreads();   // scratch (+ lut on first iter) visible
        fft_stages<-1, false>(scratch, resbuf[combo], lut, tid);
    }

    // Wiener to registers (no resbuf overwrites until all reads done)
    const float TPN = 6.28318530717958647692f / 1024.0f;
    float2 gout[2][4];
    #pragma unroll
    for (int o = 0; o < 2; ++o) {
        int u = rows[o];
        int po = selfp ? o : (1 - o);      // partner row's slot base
        float cu = cosf(TPN * (float)u);
        float c2u = 2.0f * cu * cu - 1.0f;
        float hu = 2.0f + 2.0f * cu;
        #pragma unroll
        for (int j = 0; j < 4; ++j) {
            int v = tid + (j << 8);
            int vn = (1024 - v) & 1023;
            float cv = cosf(TPN * (float)v);
            float c2v = 2.0f * cv * cv - 1.0f;
            float hv = 2.0f + 2.0f * cv;
            float grad = (2.0f - 2.0f * c2v) * hu * hu +
                         (2.0f - 2.0f * c2u) * hv * hv;
            float regs = 5.0f + 5.0f * grad;
            float G0x, G0y, G1x, G1y;
            #pragma unroll
            for (int c = 0; c < 2; ++c) {
                float2 a = resbuf[o * 2 + c][v];
                float2 b = resbuf[po * 2 + c][vn];
                float Lx = 0.5f * (a.x + b.x), Ly = 0.5f * (a.y - b.y);
                float Fx = 0.5f * (a.y + b.y), Fy = -0.5f * (a.x - b.x);
                float inv = 1.0f / (Fx * Fx + Fy * Fy + regs);
                float nx = (Fx * Lx + Fy * Ly) * inv;   // conj(F)*L
                float ny = (Fx * Ly - Fy * Lx) * inv;
                if (c == 0) { G0x = nx; G0y = ny; } else { G1x = nx; G1y = ny; }
            }
            gout[o][j] = make_float2(G0x - G1y, G0y + G1x);
        }
    }
    __syncthreads();   // all resbuf reads complete

    // inverse FFT along ky for both owned rows; write Wb[p][u][y]
    const float isc = 1.0f / 1024.0f;
    #pragma unroll
    for (int o = 0; o < 2; ++o) {
        #pragma unroll
        for (int j = 0; j < 4; ++j) scratch[tid + (j << 8)] = gout[o][j];
        __syncthreads();
        fft_stages<1, true>(scratch, resbuf[o], lut, tid);
        float4* go = (float4*)(Wb + (((size_t)p << 20) +
                                     ((size_t)rows[o] << 10)));
        #pragma unroll
        for (int h = 0; h < 2; ++h) {
            int k = (tid + (h << 8)) << 1;
            float2 v0 = resbuf[o][k], v1 = resbuf[o][k + 1];
            go[tid + (h << 8)] = make_float4(v0.x * isc, v0.y * isc,
                                             v1.x * isc, v1.y * isc);
        }
    }
}

// ---------------------------------------------------------------------------
// Final inverse pass: FFT over rows, fused 1/N scale + fftshift + threshold +
// split into two real psf planes + per-block argmax written to a PRIVATE slot
// (bm[channel*1024 + row]) — no hot atomics (R5 lesson: 1024 same-address
// device atomicMax serialized ~85us at the coherence point).
// ---------------------------------------------------------------------------
__global__ __launch_bounds__(256) void ifft_final_kernel(
        const float2* __restrict__ Wd, float* __restrict__ psf,
        ull* __restrict__ bm) {
    __shared__ float2 bufA[1024];
    __shared__ float2 bufB[1024];
    __shared__ float2 lut[768];
    __shared__ ull red[256];
    int tid = threadIdx.x;
    size_t base = (size_t)blockIdx.x << 10;
    const float4* g = (const float4*)(Wd + base);
    #pragma unroll
    for (int h = 0; h < 2; ++h) {
        float4 v = g[tid + (h << 8)];
        int k = (tid + (h << 8)) << 1;
        bufA[k]     = make_float2(v.x, v.y);
        bufA[k + 1] = make_float2(v.z, v.w);
    }
    fft_fill_lut<1>(lut, tid);
    __syncthreads();
    fft_stages<1, false>(bufA, bufB, lut, tid);
    int p = blockIdx.x >> 10;
    int y = blockIdx.x & 1023;
    int oy = (y + 512) & 1023;
    float* p0 = psf + (((size_t)(2 * p) << 20) + ((size_t)oy << 10));
    float* p1 = p0 + (1u << 20);
    const float sc = 1.0f / 1024.0f;
    ull e0 = 0, e1 = 0;
    for (int k = tid; k < 1024; k += 256) {
        float2 v = bufB[k];
        float re = v.x * sc; re = (re < THRESH) ? 0.0f : re;
        float im = v.y * sc; im = (im < THRESH) ? 0.0f : im;
        int ox = (k + 512) & 1023;
        p0[ox] = re;
        p1[ox] = im;
        unsigned int idx = ((unsigned int)oy << 10) | (unsigned int)ox;
        ull c0 = ((ull)__float_as_uint(re) << 32) | (ull)(0xFFFFFFFFu - idx);
        ull c1 = ((ull)__float_as_uint(im) << 32) | (ull)(0xFFFFFFFFu - idx);
        e0 = c0 > e0 ? c0 : e0;
        e1 = c1 > e1 ? c1 : e1;
    }
    red[tid] = e0;
    __syncthreads();
    for (int s2 = 128; s2 > 0; s2 >>= 1) {
        if (tid < s2) { ull a = red[tid], b = red[tid + s2]; red[tid] = a > b ? a : b; }
        __syncthreads();
    }
    if (tid == 0) bm[((size_t)(2 * p) << 10) + y] = red[0];
    __syncthreads();
    red[tid] = e1;
    __syncthreads();
    for (int s2 = 128; s2 > 0; s2 >>= 1) {
        if (tid < s2) { ull a = red[tid], b = red[tid + s2]; red[tid] = a > b ? a : b; }
        __syncthreads();
    }
    if (tid == 0) bm[((size_t)(2 * p + 1) << 10) + y] = red[0];
}

// ---------------------------------------------------------------------------
// In-place square transpose, 32x32 tile pairs, per plane (grid.y = plane)
// ---------------------------------------------------------------------------
__global__ __launch_bounds__(256) void transpose_kernel(float2* __restrict__ A) {
    __shared__ float2 ta[32][33];
    __shared__ float2 tb[32][33];
    float2* P = A + ((size_t)blockIdx.y << 20);
    int r = blockIdx.x, bi = 0;
    while (r >= 32 - bi) { r -= 32 - bi; ++bi; }
    int bj = bi + r;
    int tx = threadIdx.x & 31, ty = threadIdx.x >> 5;
    for (int yy = ty; yy < 32; yy += 8) {
        ta[yy][tx] = P[(size_t)(bi * 32 + yy) * SS + bj * 32 + tx];
        tb[yy][tx] = P[(size_t)(bj * 32 + yy) * SS + bi * 32 + tx];
    }
    __syncthreads();
    for (int yy = ty; yy < 32; yy += 8) {
        P[(size_t)(bi * 32 + yy) * SS + bj * 32 + tx] = tb[tx][yy];
        P[(size_t)(bj * 32 + yy) * SS + bi * 32 + tx] = ta[tx][yy];
    }
}

// ---------------------------------------------------------------------------
// Per-channel argmax finish (reduce 1024 per-block maxima) + crop 41x41
// (dynamic_slice clamp semantics) + normalize. One block per channel.
// ---------------------------------------------------------------------------
__global__ __launch_bounds__(256) void crop_kernel(
        const float* __restrict__ psf, const ull* __restrict__ bm,
        float* __restrict__ out) {
    int c = blockIdx.x;
    __shared__ ull rmax[256];
    __shared__ float red[256];
    int tid = threadIdx.x;
    ull e = 0;
    for (int i = tid; i < 1024; i += 256) {
        ull v = bm[((size_t)c << 10) + i];
        e = v > e ? v : e;
    }
    rmax[tid] = e;
    __syncthreads();
    for (int s2 = 128; s2 > 0; s2 >>= 1) {
        if (tid < s2) { ull a = rmax[tid], b = rmax[tid + s2]; rmax[tid] = a > b ? a : b; }
        __syncthreads();
    }
    unsigned int bidx = 0xFFFFFFFFu - (unsigned int)(rmax[0] & 0xFFFFFFFFull);
    int row = (int)(bidx >> 10), col = (int)(bidx & 1023);
    int r0 = row - 20; if (r0 < 0) r0 = 0; if (r0 > SS - 41) r0 = SS - 41;
    int c0 = col - 20; if (c0 < 0) c0 = 0; if (c0 > SS - 41) c0 = SS - 41;
    const float* p = psf + ((size_t)c << 20);
    float local = 0.0f;
    for (int i = tid; i < 1681; i += 256) {
        int rr = i / 41, cc = i - rr * 41;
        local += p[(size_t)(r0 + rr) * SS + c0 + cc];
    }
    red[tid] = local;
    __syncthreads();
    for (int s2 = 128; s2 > 0; s2 >>= 1) {
        if (tid < s2) red[tid] += red[tid + s2];
        __syncthreads();
    }
    float inv = 1.0f / red[0];
    for (int i = tid; i < 1681; i += 256) {
        int rr = i / 41, cc = i - rr * 41;
        out[c * 1681 + i] = p[(size_t)(r0 + rr) * SS + c0 + cc] * inv;
    }
}

// ---------------------------------------------------------------------------
extern "C" void kernel_launch(void* const* d_in, const int* in_sizes, int n_in,
                              void* d_out, int out_size, void* d_ws,
                              size_t ws_size, hipStream_t stream) {
    const float* lms = (const float*)d_in[0];
    const float* fuse = (const float*)d_in[1];
    char* ws = (char*)d_ws;
    float2* Zf = (float2*)ws;                                   // 64 MB: 8 planes
    float2* Wb = (float2*)(ws + ((size_t)64 << 20));            // 32 MB: 4 planes
    float* psf = (float*)ws;                                    // 32 MB, reuses Zf
    ull* bm = (ull*)(ws + ((size_t)33 << 20));                  // 64 KB, dead Zf region
    float* outp = (float*)d_out;

    // 1. fused blur + pack + forward row-FFT -> Zf[c][y][kx]
    blur_fft_kernel<<<8192, 256, 0, stream>>>(lms, fuse, Zf);
    // 2. transpose -> Zf[c][kx][y]
    transpose_kernel<<<dim3(528, 8), 256, 0, stream>>>(Zf);
    // 3. fused col-FFT + Wiener + inverse-ky-FFT -> Wb[p][kx][y]
    fft2_wiener_kernel<<<2048, 256, 0, stream>>>(Zf, Wb);
    // 4. transpose -> Wb[p][y][kx]
    transpose_kernel<<<dim3(528, 4), 256, 0, stream>>>(Wb);
    // 5. inverse kx-FFT + shift/threshold/split/block-argmax
    ifft_final_kernel<<<4096, 256, 0, stream>>>(Wb, psf, bm);
    // 6. argmax finish + crop/normalize
    crop_kernel<<<8, 256, 0, stream>>>(psf, bm, outp);
}

// Round 8
// 232.403 us; speedup vs baseline: 1.4528x; 1.0611x over previous
//
#include <hip/hip_runtime.h>
#include <math.h>

#define SS 1024
#define NC 8
#define BWD 170
#define THRESH 1e-4f

typedef unsigned long long ull;

__device__ __forceinline__ float2 cmul(float2 a, float2 b) {
    return make_float2(a.x * b.x - a.y * b.y, a.x * b.y + a.y * b.x);
}

// ---------------------------------------------------------------------------
// 1024-point Stockham RADIX-4 FFT pieces. 256 threads, 5 stages.
// lut[k] = exp(DIRSIGN * 2*pi*i*k/1024), k in [0,768).
// CONJ=true conjugates the twiddles at use (inverse FFT from a forward lut);
// pair it with DIRSIGN=+1 semantics in the butterfly.
// Caller fills bufA + lut then __syncthreads(); result lands in bufB.
// ---------------------------------------------------------------------------
template <int DIRSIGN>
__device__ __forceinline__ void fft_fill_lut(float2* lut, int tid) {
    for (int i = tid; i < 768; i += 256) {
        float ang = (float)DIRSIGN * 6.28318530717958647692f * (float)i *
                    (1.0f / 1024.0f);
        float sv, cv;
        sincosf(ang, &sv, &cv);
        lut[i] = make_float2(cv, sv);
    }
}

template <int DIRSIGN, bool CONJ>
__device__ __forceinline__ void fft_stages(float2* bufA, float2* bufB,
                                           const float2* lut, int tid) {
    float2* src = bufA;
    float2* dst = bufB;
    #pragma unroll
    for (int t = 0; t < 5; ++t) {
        int s = 1 << (2 * t);
        int k = tid & ~(s - 1);           // p*s, twiddle index
        float2 a = src[tid];
        float2 b = src[tid + 256];
        float2 c = src[tid + 512];
        float2 d = src[tid + 768];
        float2 apc = make_float2(a.x + c.x, a.y + c.y);
        float2 amc = make_float2(a.x - c.x, a.y - c.y);
        float2 bpd = make_float2(b.x + d.x, b.y + d.y);
        float2 jb  = make_float2(-(b.y - d.y), b.x - d.x);   // i*(b-d)
        float2 t1, t3;
        if (DIRSIGN == -1) {
            t1 = make_float2(amc.x - jb.x, amc.y - jb.y);
            t3 = make_float2(amc.x + jb.x, amc.y + jb.y);
        } else {
            t1 = make_float2(amc.x + jb.x, amc.y + jb.y);
            t3 = make_float2(amc.x - jb.x, amc.y - jb.y);
        }
        float2 w1 = lut[k], w2 = lut[2 * k], w3 = lut[3 * k];
        if (CONJ) { w1.y = -w1.y; w2.y = -w2.y; w3.y = -w3.y; }
        int base = tid + 3 * k;           // q + 4*s*p
        dst[base]         = make_float2(apc.x + bpd.x, apc.y + bpd.y);
        dst[base + s]     = cmul(t1, w1);
        dst[base + 2 * s] = cmul(make_float2(apc.x - bpd.x, apc.y - bpd.y), w2);
        dst[base + 3 * s] = cmul(t3, w3);
        __syncthreads();
        float2* tmp = src; src = dst; dst = tmp;
    }
    // 5 stages (odd) -> final result in bufB
}

// LDS padding for the H-blur row buffers: +1 word every 32 breaks the
// lane-stride-4 (8-way) bank conflict of rowl[4*tid+k+j] reads.
#define PIDX(r) ((r) + ((r) >> 5))

// ---------------------------------------------------------------------------
// Fused blur + alpha blend + pack + forward row FFT. Block = (channel, row).
// XCD-band swizzle: y = (blk&7)*128 + ((blk>>3)&127) keeps adjacent rows on
// one XCD's L2 so the 7-row V-blur halo is fetched once per band, not once
// per row per XCD (R7: FETCH 147MB on 36MB logical = cross-XCD duplication).
// V-blur in registers (7 float4 row loads; column halo V-blur is exactly 0
// because cols <0 / >=1024 are zero-padded), H-blur via one LDS row,
// alpha blend, pack Z = lms_e + i*fuse_e, 1024-pt FFT, write Zf[c][y][kx].
// Interior rows (alpha==1 for threads' cols): skip the 6 extra row loads.
// ---------------------------------------------------------------------------
__global__ __launch_bounds__(256) void blur_fft_kernel(
        const float* __restrict__ lms, const float* __restrict__ fuse,
        float2* __restrict__ Zf) {
    __shared__ float2 bufA[1024];      // FFT input
    __shared__ float smemB[2136];      // aliases: rowl/rowf (padded), FFT bufB
    __shared__ float2 lut[768];
    float2* bufB = (float2*)smemB;
    float* rowl = smemB;               // padded idx = PIDX(col+3), col -3..1026
    float* rowf = smemB + 1068;
    int tid = threadIdx.x;
    int g = blockIdx.x;
    int c = g >> 10;
    int y = (g & 7) * 128 + ((g >> 3) & 127);   // XCD band swizzle
    const float* L = lms + ((size_t)c << 20);
    const float* F = fuse + ((size_t)c << 20);
    int x0 = tid << 2;

    // Gaussian weights (sigma=1, ks=7)
    double e1 = exp(-0.5), e2 = exp(-2.0), e3 = exp(-4.5);
    double sm = 1.0 + 2.0 * (e1 + e2 + e3);
    float w[7] = { (float)(e3 / sm), (float)(e2 / sm), (float)(e1 / sm),
                   (float)(1.0 / sm),
                   (float)(e1 / sm), (float)(e2 / sm), (float)(e3 / sm) };

    bool rowInt = (y >= BWD) && (y <= SS - 1 - BWD);
    // skipLoads threads: cols 180..843, all alpha==1, nobody reads their
    // rowl entries (H-blur readers are tid<=43 / >=212 reading cols
    // <=178 / >=845, written by tid<=44 / >=211).
    bool skipLoads = rowInt && (tid >= 45) && (tid <= 210);
    bool doH = !rowInt || (tid <= 43) || (tid >= 212);

    float4 cl, cf;
    if (skipLoads) {
        cl = *(const float4*)&L[((size_t)y << 10) + x0];
        cf = *(const float4*)&F[((size_t)y << 10) + x0];
    } else {
        float4 lv[7], fv[7];
        #pragma unroll
        for (int r = 0; r < 7; ++r) {
            int gy = y - 3 + r;
            if (gy >= 0 && gy < SS) {
                lv[r] = *(const float4*)&L[((size_t)gy << 10) + x0];
                fv[r] = *(const float4*)&F[((size_t)gy << 10) + x0];
            } else {
                lv[r] = make_float4(0.f, 0.f, 0.f, 0.f);
                fv[r] = make_float4(0.f, 0.f, 0.f, 0.f);
            }
        }
        cl = lv[3]; cf = fv[3];
        #pragma unroll
        for (int j = 0; j < 4; ++j) {
            float a = 0.f, b = 0.f;
            #pragma unroll
            for (int r = 0; r < 7; ++r) {
                a += w[r] * (&lv[r].x)[j];
                b += w[r] * (&fv[r].x)[j];
            }
            rowl[PIDX(3 + x0 + j)] = a;
            rowf[PIDX(3 + x0 + j)] = b;
        }
    }
    if (tid < 3) {
        rowl[PIDX(tid)] = 0.f; rowf[PIDX(tid)] = 0.f;
        rowl[PIDX(1027 + tid)] = 0.f; rowf[PIDX(1027 + tid)] = 0.f;
    }
    fft_fill_lut<-1>(lut, tid);
    __syncthreads();

    float bl[4] = {0.f, 0.f, 0.f, 0.f}, bf[4] = {0.f, 0.f, 0.f, 0.f};
    if (doH) {
        #pragma unroll
        for (int k = 0; k < 4; ++k) {
            float a = 0.f, b = 0.f;
            #pragma unroll
            for (int j = 0; j < 7; ++j) {
                a += w[j] * rowl[PIDX(x0 + k + j)];
                b += w[j] * rowf[PIDX(x0 + k + j)];
            }
            bl[k] = a; bf[k] = b;
        }
    }
    int gyv = (y < BWD) ? y : ((SS - 1 - y) < BWD ? (SS - 1 - y) : -1);
    #pragma unroll
    for (int k = 0; k < 4; ++k) {
        int x = x0 + k;
        int gx = (x < BWD) ? x : ((SS - 1 - x) < BWD ? (SS - 1 - x) : -1);
        int m = gyv > gx ? gyv : gx;
        float a = (m >= 0) ? (float)m / (float)BWD : 1.0f;
        bufA[x] = make_float2(a * (&cl.x)[k] + (1.0f - a) * bl[k],
                              a * (&cf.x)[k] + (1.0f - a) * bf[k]);
    }
    __syncthreads();   // bufA ready; rowl/rowf reads done -> bufB reusable
    fft_stages<-1, false>(bufA, bufB, lut, tid);
    float4* go = (float4*)(Zf + (((size_t)c << 20) + ((size_t)y << 10)));
    #pragma unroll
    for (int h = 0; h < 2; ++h) {
        int k = (tid + (h << 8)) << 1;
        float2 v0 = bufB[k], v1 = bufB[k + 1];
        go[tid + (h << 8)] = make_float4(v0.x, v0.y, v1.x, v1.y);
    }
}

// ---------------------------------------------------------------------------
// Fused second forward FFT + Wiener + first inverse FFT (along ky).
// One block owns a conjugate row pair (u, 1024-u) for a channel pair p:
// 4 forward FFTs into LDS slots, Wiener to registers, then 2 inverse FFTs
// (conjugated twiddles) and write Wb[p][u][y] directly — the standalone
// inverse-rows pass is gone. Block i=0 handles self-paired rows {0, 512}.
// ---------------------------------------------------------------------------
__global__ __launch_bounds__(256) void fft2_wiener_kernel(
        const float2* __restrict__ Z, float2* __restrict__ Wb) {
    __shared__ float2 resbuf[4][1024];
    __shared__ float2 scratch[1024];
    __shared__ float2 lut[768];
    int tid = threadIdx.x;
    int p = blockIdx.x >> 9;          // channel pair 0..3
    int i = blockIdx.x & 511;
    int rows[2];
    rows[0] = (i == 0) ? 0 : i;
    rows[1] = (i == 0) ? 512 : 1024 - i;
    bool selfp = (i == 0);

    fft_fill_lut<-1>(lut, tid);

    // prefetch combo 0 (row0, ch0)
    const float4* g = (const float4*)(Z + (((size_t)(2 * p) << 20) +
                                           ((size_t)rows[0] << 10)));
    float4 ra = g[tid], rb = g[tid + 256];
    #pragma unroll
    for (int combo = 0; combo < 4; ++combo) {
        int k0 = tid << 1, k1 = (tid + 256) << 1;
        scratch[k0]     = make_float2(ra.x, ra.y);
        scratch[k0 + 1] = make_float2(ra.z, ra.w);
        scratch[k1]     = make_float2(rb.x, rb.y);
        scratch[k1 + 1] = make_float2(rb.z, rb.w);
        if (combo < 3) {
            int nr = (combo + 1) >> 1, nc = (combo + 1) & 1;
            const float4* gn = (const float4*)(Z +
                (((size_t)(2 * p + nc) << 20) + ((size_t)rows[nr] << 10)));
            ra = gn[tid];
            rb = gn[tid + 256];
        }
        __syncthreads();   // scratch (+ lut on first iter) visible
        fft_stages<-1, false>(scratch, resbuf[combo], lut, tid);
    }

    // Wiener to registers (no resbuf overwrites until all reads done)
    const float TPN = 6.28318530717958647692f / 1024.0f;
    float2 gout[2][4];
    #pragma unroll
    for (int o = 0; o < 2; ++o) {
        int u = rows[o];
        int po = selfp ? o : (1 - o);      // partner row's slot base
        float cu = cosf(TPN * (float)u);
        float c2u = 2.0f * cu * cu - 1.0f;
        float hu = 2.0f + 2.0f * cu;
        #pragma unroll
        for (int j = 0; j < 4; ++j) {
            int v = tid + (j << 8);
            int vn = (1024 - v) & 1023;
            float cv = cosf(TPN * (float)v);
            float c2v = 2.0f * cv * cv - 1.0f;
            float hv = 2.0f + 2.0f * cv;
            float grad = (2.0f - 2.0f * c2v) * hu * hu +
                         (2.0f - 2.0f * c2u) * hv * hv;
            float regs = 5.0f + 5.0f * grad;
            float G0x, G0y, G1x, G1y;
            #pragma unroll
            for (int c = 0; c < 2; ++c) {
                float2 a = resbuf[o * 2 + c][v];
                float2 b = resbuf[po * 2 + c][vn];
                float Lx = 0.5f * (a.x + b.x), Ly = 0.5f * (a.y - b.y);
                float Fx = 0.5f * (a.y + b.y), Fy = -0.5f * (a.x - b.x);
                float inv = 1.0f / (Fx * Fx + Fy * Fy + regs);
                float nx = (Fx * Lx + Fy * Ly) * inv;   // conj(F)*L
                float ny = (Fx * Ly - Fy * Lx) * inv;
                if (c == 0) { G0x = nx; G0y = ny; } else { G1x = nx; G1y = ny; }
            }
            gout[o][j] = make_float2(G0x - G1y, G0y + G1x);
        }
    }
    __syncthreads();   // all resbuf reads complete

    // inverse FFT along ky for both owned rows; write Wb[p][u][y]
    const float isc = 1.0f / 1024.0f;
    #pragma unroll
    for (int o = 0; o < 2; ++o) {
        #pragma unroll
        for (int j = 0; j < 4; ++j) scratch[tid + (j << 8)] = gout[o][j];
        __syncthreads();
        fft_stages<1, true>(scratch, resbuf[o], lut, tid);
        float4* go = (float4*)(Wb + (((size_t)p << 20) +
                                     ((size_t)rows[o] << 10)));
        #pragma unroll
        for (int h = 0; h < 2; ++h) {
            int k = (tid + (h << 8)) << 1;
            float2 v0 = resbuf[o][k], v1 = resbuf[o][k + 1];
            go[tid + (h << 8)] = make_float4(v0.x * isc, v0.y * isc,
                                             v1.x * isc, v1.y * isc);
        }
    }
}

// ---------------------------------------------------------------------------
// Final inverse pass: FFT over rows, fused 1/N scale + fftshift + threshold +
// split into two real psf planes + per-block argmax written to a PRIVATE slot
// (bm[channel*1024 + row]) — no hot atomics (R5 lesson: 1024 same-address
// device atomicMax serialized ~85us at the coherence point).
// ---------------------------------------------------------------------------
__global__ __launch_bounds__(256) void ifft_final_kernel(
        const float2* __restrict__ Wd, float* __restrict__ psf,
        ull* __restrict__ bm) {
    __shared__ float2 bufA[1024];
    __shared__ float2 bufB[1024];
    __shared__ float2 lut[768];
    __shared__ ull red[256];
    int tid = threadIdx.x;
    size_t base = (size_t)blockIdx.x << 10;
    const float4* g = (const float4*)(Wd + base);
    #pragma unroll
    for (int h = 0; h < 2; ++h) {
        float4 v = g[tid + (h << 8)];
        int k = (tid + (h << 8)) << 1;
        bufA[k]     = make_float2(v.x, v.y);
        bufA[k + 1] = make_float2(v.z, v.w);
    }
    fft_fill_lut<1>(lut, tid);
    __syncthreads();
    fft_stages<1, false>(bufA, bufB, lut, tid);
    int p = blockIdx.x >> 10;
    int y = blockIdx.x & 1023;
    int oy = (y + 512) & 1023;
    float* p0 = psf + (((size_t)(2 * p) << 20) + ((size_t)oy << 10));
    float* p1 = p0 + (1u << 20);
    const float sc = 1.0f / 1024.0f;
    ull e0 = 0, e1 = 0;
    for (int k = tid; k < 1024; k += 256) {
        float2 v = bufB[k];
        float re = v.x * sc; re = (re < THRESH) ? 0.0f : re;
        float im = v.y * sc; im = (im < THRESH) ? 0.0f : im;
        int ox = (k + 512) & 1023;
        p0[ox] = re;
        p1[ox] = im;
        unsigned int idx = ((unsigned int)oy << 10) | (unsigned int)ox;
        ull c0 = ((ull)__float_as_uint(re) << 32) | (ull)(0xFFFFFFFFu - idx);
        ull c1 = ((ull)__float_as_uint(im) << 32) | (ull)(0xFFFFFFFFu - idx);
        e0 = c0 > e0 ? c0 : e0;
        e1 = c1 > e1 ? c1 : e1;
    }
    red[tid] = e0;
    __syncthreads();
    for (int s2 = 128; s2 > 0; s2 >>= 1) {
        if (tid < s2) { ull a = red[tid], b = red[tid + s2]; red[tid] = a > b ? a : b; }
        __syncthreads();
    }
    if (tid == 0) bm[((size_t)(2 * p) << 10) + y] = red[0];
    __syncthreads();
    red[tid] = e1;
    __syncthreads();
    for (int s2 = 128; s2 > 0; s2 >>= 1) {
        if (tid < s2) { ull a = red[tid], b = red[tid + s2]; red[tid] = a > b ? a : b; }
        __syncthreads();
    }
    if (tid == 0) bm[((size_t)(2 * p + 1) << 10) + y] = red[0];
}

// ---------------------------------------------------------------------------
// In-place square transpose, 32x32 tile pairs, per plane (grid.y = plane)
// ---------------------------------------------------------------------------
__global__ __launch_bounds__(256) void transpose_kernel(float2* __restrict__ A) {
    __shared__ float2 ta[32][33];
    __shared__ float2 tb[32][33];
    float2* P = A + ((size_t)blockIdx.y << 20);
    int r = blockIdx.x, bi = 0;
    while (r >= 32 - bi) { r -= 32 - bi; ++bi; }
    int bj = bi + r;
    int tx = threadIdx.x & 31, ty = threadIdx.x >> 5;
    for (int yy = ty; yy < 32; yy += 8) {
        ta[yy][tx] = P[(size_t)(bi * 32 + yy) * SS + bj * 32 + tx];
        tb[yy][tx] = P[(size_t)(bj * 32 + yy) * SS + bi * 32 + tx];
    }
    __syncthreads();
    for (int yy = ty; yy < 32; yy += 8) {
        P[(size_t)(bi * 32 + yy) * SS + bj * 32 + tx] = tb[tx][yy];
        P[(size_t)(bj * 32 + yy) * SS + bi * 32 + tx] = ta[tx][yy];
    }
}

// ---------------------------------------------------------------------------
// Per-channel argmax finish (reduce 1024 per-block maxima) + crop 41x41
// (dynamic_slice clamp semantics) + normalize. One block per channel.
// ---------------------------------------------------------------------------
__global__ __launch_bounds__(256) void crop_kernel(
        const float* __restrict__ psf, const ull* __restrict__ bm,
        float* __restrict__ out) {
    int c = blockIdx.x;
    __shared__ ull rmax[256];
    __shared__ float red[256];
    int tid = threadIdx.x;
    ull e = 0;
    for (int i = tid; i < 1024; i += 256) {
        ull v = bm[((size_t)c << 10) + i];
        e = v > e ? v : e;
    }
    rmax[tid] = e;
    __syncthreads();
    for (int s2 = 128; s2 > 0; s2 >>= 1) {
        if (tid < s2) { ull a = rmax[tid], b = rmax[tid + s2]; rmax[tid] = a > b ? a : b; }
        __syncthreads();
    }
    unsigned int bidx = 0xFFFFFFFFu - (unsigned int)(rmax[0] & 0xFFFFFFFFull);
    int row = (int)(bidx >> 10), col = (int)(bidx & 1023);
    int r0 = row - 20; if (r0 < 0) r0 = 0; if (r0 > SS - 41) r0 = SS - 41;
    int c0 = col - 20; if (c0 < 0) c0 = 0; if (c0 > SS - 41) c0 = SS - 41;
    const float* p = psf + ((size_t)c << 20);
    float local = 0.0f;
    for (int i = tid; i < 1681; i += 256) {
        int rr = i / 41, cc = i - rr * 41;
        local += p[(size_t)(r0 + rr) * SS + c0 + cc];
    }
    red[tid] = local;
    __syncthreads();
    for (int s2 = 128; s2 > 0; s2 >>= 1) {
        if (tid < s2) red[tid] += red[tid + s2];
        __syncthreads();
    }
    float inv = 1.0f / red[0];
    for (int i = tid; i < 1681; i += 256) {
        int rr = i / 41, cc = i - rr * 41;
        out[c * 1681 + i] = p[(size_t)(r0 + rr) * SS + c0 + cc] * inv;
    }
}

// ---------------------------------------------------------------------------
extern "C" void kernel_launch(void* const* d_in, const int* in_sizes, int n_in,
                              void* d_out, int out_size, void* d_ws,
                              size_t ws_size, hipStream_t stream) {
    const float* lms = (const float*)d_in[0];
    const float* fuse = (const float*)d_in[1];
    char* ws = (char*)d_ws;
    float2* Zf = (float2*)ws;                                   // 64 MB: 8 planes
    float2* Wb = (float2*)(ws + ((size_t)64 << 20));            // 32 MB: 4 planes
    float* psf = (float*)ws;                                    // 32 MB, reuses Zf
    ull* bm = (ull*)(ws + ((size_t)33 << 20));                  // 64 KB, dead Zf region
    float* outp = (float*)d_out;

    // 1. fused blur + pack + forward row-FFT -> Zf[c][y][kx]
    blur_fft_kernel<<<8192, 256, 0, stream>>>(lms, fuse, Zf);
    // 2. transpose -> Zf[c][kx][y]
    transpose_kernel<<<dim3(528, 8), 256, 0, stream>>>(Zf);
    // 3. fused col-FFT + Wiener + inverse-ky-FFT -> Wb[p][kx][y]
    fft2_wiener_kernel<<<2048, 256, 0, stream>>>(Zf, Wb);
    // 4. transpose -> Wb[p][y][kx]
    transpose_kernel<<<dim3(528, 4), 256, 0, stream>>>(Wb);
    // 5. inverse kx-FFT + shift/threshold/split/block-argmax
    ifft_final_kernel<<<4096, 256, 0, stream>>>(Wb, psf, bm);
    // 6. argmax finish + crop/normalize
    crop_kernel<<<8, 256, 0, stream>>>(psf, bm, outp);
}

// Round 9
// 232.006 us; speedup vs baseline: 1.4553x; 1.0017x over previous
//
#include <hip/hip_runtime.h>
#include <math.h>

#define SS 1024
#define NC 8
#define BWD 170
#define THRESH 1e-4f

typedef unsigned long long ull;

__device__ __forceinline__ float2 cmul(float2 a, float2 b) {
    return make_float2(a.x * b.x - a.y * b.y, a.x * b.y + a.y * b.x);
}

// ---------------------------------------------------------------------------
// FFT LDS padding: +1 float2 every 8 breaks the stride-4 (stage 0) and
// stride-16 (stage 1) Stockham write patterns (were 16-way bank conflicts).
// Padded 1024-pt buffer needs SP(1023)+1 = 1151 -> use 1152 float2.
// ---------------------------------------------------------------------------
#define SP(i) ((i) + ((i) >> 3))
#define FFTBUF 1152

// ---------------------------------------------------------------------------
// 1024-point Stockham RADIX-4 FFT pieces. 256 threads, 5 stages.
// lut[k] = exp(DIRSIGN * 2*pi*i*k/1024), k in [0,768) — filled with HW
// v_sin/v_cos (input in revolutions, args in [0,0.75) need no reduction;
// ~1e-6 abs err, 20x inside the 1.57e-4 test threshold).
// CONJ=true conjugates twiddles at use (inverse FFT from a forward lut).
// Caller fills bufA (SP-indexed) + lut then __syncthreads(); result in bufB.
// ---------------------------------------------------------------------------
template <int DIRSIGN>
__device__ __forceinline__ void fft_fill_lut(float2* lut, int tid) {
    for (int i = tid; i < 768; i += 256) {
        float rev = (float)i * (1.0f / 1024.0f);   // revolutions
        float cv = __builtin_amdgcn_cosf(rev);
        float sv = __builtin_amdgcn_sinf(rev);
        lut[i] = make_float2(cv, (float)DIRSIGN * sv);
    }
}

template <int DIRSIGN, bool CONJ>
__device__ __forceinline__ void fft_stages(float2* bufA, float2* bufB,
                                           const float2* lut, int tid) {
    float2* src = bufA;
    float2* dst = bufB;
    #pragma unroll
    for (int t = 0; t < 5; ++t) {
        int s = 1 << (2 * t);
        int k = tid & ~(s - 1);           // p*s, twiddle index
        float2 a = src[SP(tid)];
        float2 b = src[SP(tid + 256)];
        float2 c = src[SP(tid + 512)];
        float2 d = src[SP(tid + 768)];
        float2 apc = make_float2(a.x + c.x, a.y + c.y);
        float2 amc = make_float2(a.x - c.x, a.y - c.y);
        float2 bpd = make_float2(b.x + d.x, b.y + d.y);
        float2 jb  = make_float2(-(b.y - d.y), b.x - d.x);   // i*(b-d)
        float2 t1, t3;
        if (DIRSIGN == -1) {
            t1 = make_float2(amc.x - jb.x, amc.y - jb.y);
            t3 = make_float2(amc.x + jb.x, amc.y + jb.y);
        } else {
            t1 = make_float2(amc.x + jb.x, amc.y + jb.y);
            t3 = make_float2(amc.x - jb.x, amc.y - jb.y);
        }
        float2 w1 = lut[k], w2 = lut[2 * k], w3 = lut[3 * k];
        if (CONJ) { w1.y = -w1.y; w2.y = -w2.y; w3.y = -w3.y; }
        int base = tid + 3 * k;           // q + 4*s*p
        dst[SP(base)]         = make_float2(apc.x + bpd.x, apc.y + bpd.y);
        dst[SP(base + s)]     = cmul(t1, w1);
        dst[SP(base + 2 * s)] = cmul(make_float2(apc.x - bpd.x, apc.y - bpd.y), w2);
        dst[SP(base + 3 * s)] = cmul(t3, w3);
        __syncthreads();
        float2* tmp = src; src = dst; dst = tmp;
    }
    // 5 stages (odd) -> final result in bufB (SP-indexed)
}

// LDS padding for the H-blur row buffers (float units, stride-4 reads)
#define PIDX(r) ((r) + ((r) >> 5))

// ---------------------------------------------------------------------------
// Fused blur + alpha blend + pack + forward row FFT. Block = (channel, row).
// XCD-band swizzle: y = (blk&7)*128 + ((blk>>3)&127) keeps adjacent rows on
// one XCD's L2 so the 7-row V-blur halo is fetched once per band (R8: FETCH
// 147->33.5MB). V-blur in registers, H-blur via one LDS row, alpha blend,
// pack Z = lms_e + i*fuse_e, 1024-pt FFT, write Zf[c][y][kx].
// ---------------------------------------------------------------------------
__global__ __launch_bounds__(256) void blur_fft_kernel(
        const float* __restrict__ lms, const float* __restrict__ fuse,
        float2* __restrict__ Zf) {
    __shared__ float2 bufA[FFTBUF];    // FFT input (SP-indexed)
    __shared__ float smemB[2304];      // aliases: rowl/rowf (PIDX), FFT bufB
    __shared__ float2 lut[768];
    float2* bufB = (float2*)smemB;
    float* rowl = smemB;               // PIDX(col+3), col -3..1026
    float* rowf = smemB + 1068;
    int tid = threadIdx.x;
    int g = blockIdx.x;
    int c = g >> 10;
    int y = (g & 7) * 128 + ((g >> 3) & 127);   // XCD band swizzle
    const float* L = lms + ((size_t)c << 20);
    const float* F = fuse + ((size_t)c << 20);
    int x0 = tid << 2;

    // Gaussian weights (sigma=1, ks=7)
    double e1 = exp(-0.5), e2 = exp(-2.0), e3 = exp(-4.5);
    double sm = 1.0 + 2.0 * (e1 + e2 + e3);
    float w[7] = { (float)(e3 / sm), (float)(e2 / sm), (float)(e1 / sm),
                   (float)(1.0 / sm),
                   (float)(e1 / sm), (float)(e2 / sm), (float)(e3 / sm) };

    bool rowInt = (y >= BWD) && (y <= SS - 1 - BWD);
    bool skipLoads = rowInt && (tid >= 45) && (tid <= 210);
    bool doH = !rowInt || (tid <= 43) || (tid >= 212);

    float4 cl, cf;
    if (skipLoads) {
        cl = *(const float4*)&L[((size_t)y << 10) + x0];
        cf = *(const float4*)&F[((size_t)y << 10) + x0];
    } else {
        float4 lv[7], fv[7];
        #pragma unroll
        for (int r = 0; r < 7; ++r) {
            int gy = y - 3 + r;
            if (gy >= 0 && gy < SS) {
                lv[r] = *(const float4*)&L[((size_t)gy << 10) + x0];
                fv[r] = *(const float4*)&F[((size_t)gy << 10) + x0];
            } else {
                lv[r] = make_float4(0.f, 0.f, 0.f, 0.f);
                fv[r] = make_float4(0.f, 0.f, 0.f, 0.f);
            }
        }
        cl = lv[3]; cf = fv[3];
        #pragma unroll
        for (int j = 0; j < 4; ++j) {
            float a = 0.f, b = 0.f;
            #pragma unroll
            for (int r = 0; r < 7; ++r) {
                a += w[r] * (&lv[r].x)[j];
                b += w[r] * (&fv[r].x)[j];
            }
            rowl[PIDX(3 + x0 + j)] = a;
            rowf[PIDX(3 + x0 + j)] = b;
        }
    }
    if (tid < 3) {
        rowl[PIDX(tid)] = 0.f; rowf[PIDX(tid)] = 0.f;
        rowl[PIDX(1027 + tid)] = 0.f; rowf[PIDX(1027 + tid)] = 0.f;
    }
    fft_fill_lut<-1>(lut, tid);
    __syncthreads();

    float bl[4] = {0.f, 0.f, 0.f, 0.f}, bf[4] = {0.f, 0.f, 0.f, 0.f};
    if (doH) {
        #pragma unroll
        for (int k = 0; k < 4; ++k) {
            float a = 0.f, b = 0.f;
            #pragma unroll
            for (int j = 0; j < 7; ++j) {
                a += w[j] * rowl[PIDX(x0 + k + j)];
                b += w[j] * rowf[PIDX(x0 + k + j)];
            }
            bl[k] = a; bf[k] = b;
        }
    }
    int gyv = (y < BWD) ? y : ((SS - 1 - y) < BWD ? (SS - 1 - y) : -1);
    #pragma unroll
    for (int k = 0; k < 4; ++k) {
        int x = x0 + k;
        int gx = (x < BWD) ? x : ((SS - 1 - x) < BWD ? (SS - 1 - x) : -1);
        int m = gyv > gx ? gyv : gx;
        float a = (m >= 0) ? (float)m / (float)BWD : 1.0f;
        bufA[SP(x)] = make_float2(a * (&cl.x)[k] + (1.0f - a) * bl[k],
                                  a * (&cf.x)[k] + (1.0f - a) * bf[k]);
    }
    __syncthreads();   // bufA ready; rowl/rowf reads done -> bufB reusable
    fft_stages<-1, false>(bufA, bufB, lut, tid);
    float4* go = (float4*)(Zf + (((size_t)c << 20) + ((size_t)y << 10)));
    #pragma unroll
    for (int h = 0; h < 2; ++h) {
        int k = (tid + (h << 8)) << 1;
        float2 v0 = bufB[SP(k)], v1 = bufB[SP(k + 1)];
        go[tid + (h << 8)] = make_float4(v0.x, v0.y, v1.x, v1.y);
    }
}

// ---------------------------------------------------------------------------
// Fused second forward FFT + Wiener + first inverse FFT (along ky).
// One block owns a conjugate row pair (u, 1024-u) for a channel pair p:
// 4 forward FFTs into LDS slots, Wiener to registers, then 2 inverse FFTs
// (conjugated twiddles) and write Wb[p][u][y] directly.
// Block i=0 handles self-paired rows {0, 512}.
// ---------------------------------------------------------------------------
__global__ __launch_bounds__(256) void fft2_wiener_kernel(
        const float2* __restrict__ Z, float2* __restrict__ Wb) {
    __shared__ float2 resbuf[4][FFTBUF];
    __shared__ float2 scratch[FFTBUF];
    __shared__ float2 lut[768];
    int tid = threadIdx.x;
    int p = blockIdx.x >> 9;          // channel pair 0..3
    int i = blockIdx.x & 511;
    int rows[2];
    rows[0] = (i == 0) ? 0 : i;
    rows[1] = (i == 0) ? 512 : 1024 - i;
    bool selfp = (i == 0);

    fft_fill_lut<-1>(lut, tid);

    // prefetch combo 0 (row0, ch0)
    const float4* g = (const float4*)(Z + (((size_t)(2 * p) << 20) +
                                           ((size_t)rows[0] << 10)));
    float4 ra = g[tid], rb = g[tid + 256];
    #pragma unroll
    for (int combo = 0; combo < 4; ++combo) {
        int k0 = tid << 1, k1 = (tid + 256) << 1;
        scratch[SP(k0)]     = make_float2(ra.x, ra.y);
        scratch[SP(k0 + 1)] = make_float2(ra.z, ra.w);
        scratch[SP(k1)]     = make_float2(rb.x, rb.y);
        scratch[SP(k1 + 1)] = make_float2(rb.z, rb.w);
        if (combo < 3) {
            int nr = (combo + 1) >> 1, nc = (combo + 1) & 1;
            const float4* gn = (const float4*)(Z +
                (((size_t)(2 * p + nc) << 20) + ((size_t)rows[nr] << 10)));
            ra = gn[tid];
            rb = gn[tid + 256];
        }
        __syncthreads();   // scratch (+ lut on first iter) visible
        fft_stages<-1, false>(scratch, resbuf[combo], lut, tid);
    }

    // Wiener to registers (no resbuf overwrites until all reads done)
    const float TPN = 6.28318530717958647692f / 1024.0f;
    float2 gout[2][4];
    #pragma unroll
    for (int o = 0; o < 2; ++o) {
        int u = rows[o];
        int po = selfp ? o : (1 - o);      // partner row's slot base
        float cu = cosf(TPN * (float)u);
        float c2u = 2.0f * cu * cu - 1.0f;
        float hu = 2.0f + 2.0f * cu;
        #pragma unroll
        for (int j = 0; j < 4; ++j) {
            int v = tid + (j << 8);
            int vn = (1024 - v) & 1023;
            float cv = cosf(TPN * (float)v);
            float c2v = 2.0f * cv * cv - 1.0f;
            float hv = 2.0f + 2.0f * cv;
            float grad = (2.0f - 2.0f * c2v) * hu * hu +
                         (2.0f - 2.0f * c2u) * hv * hv;
            float regs = 5.0f + 5.0f * grad;
            float G0x, G0y, G1x, G1y;
            #pragma unroll
            for (int c = 0; c < 2; ++c) {
                float2 a = resbuf[o * 2 + c][SP(v)];
                float2 b = resbuf[po * 2 + c][SP(vn)];
                float Lx = 0.5f * (a.x + b.x), Ly = 0.5f * (a.y - b.y);
                float Fx = 0.5f * (a.y + b.y), Fy = -0.5f * (a.x - b.x);
                float inv = 1.0f / (Fx * Fx + Fy * Fy + regs);
                float nx = (Fx * Lx + Fy * Ly) * inv;   // conj(F)*L
                float ny = (Fx * Ly - Fy * Lx) * inv;
                if (c == 0) { G0x = nx; G0y = ny; } else { G1x = nx; G1y = ny; }
            }
            gout[o][j] = make_float2(G0x - G1y, G0y + G1x);
        }
    }
    __syncthreads();   // all resbuf reads complete

    // inverse FFT along ky for both owned rows; write Wb[p][u][y]
    const float isc = 1.0f / 1024.0f;
    #pragma unroll
    for (int o = 0; o < 2; ++o) {
        #pragma unroll
        for (int j = 0; j < 4; ++j) scratch[SP(tid + (j << 8))] = gout[o][j];
        __syncthreads();
        fft_stages<1, true>(scratch, resbuf[o], lut, tid);
        float4* go = (float4*)(Wb + (((size_t)p << 20) +
                                     ((size_t)rows[o] << 10)));
        #pragma unroll
        for (int h = 0; h < 2; ++h) {
            int k = (tid + (h << 8)) << 1;
            float2 v0 = resbuf[o][SP(k)], v1 = resbuf[o][SP(k + 1)];
            go[tid + (h << 8)] = make_float4(v0.x * isc, v0.y * isc,
                                             v1.x * isc, v1.y * isc);
        }
    }
}

// ---------------------------------------------------------------------------
// Final inverse pass: FFT over rows, fused 1/N scale + fftshift + threshold +
// split into two real psf planes + per-block argmax written to a PRIVATE slot
// (bm[channel*1024 + row]) — no hot atomics (R5 lesson: 1024 same-address
// device atomicMax serialized ~85us at the coherence point).
// ---------------------------------------------------------------------------
__global__ __launch_bounds__(256) void ifft_final_kernel(
        const float2* __restrict__ Wd, float* __restrict__ psf,
        ull* __restrict__ bm) {
    __shared__ float2 bufA[FFTBUF];
    __shared__ float2 bufB[FFTBUF];
    __shared__ float2 lut[768];
    __shared__ ull red[256];
    int tid = threadIdx.x;
    size_t base = (size_t)blockIdx.x << 10;
    const float4* g = (const float4*)(Wd + base);
    #pragma unroll
    for (int h = 0; h < 2; ++h) {
        float4 v = g[tid + (h << 8)];
        int k = (tid + (h << 8)) << 1;
        bufA[SP(k)]     = make_float2(v.x, v.y);
        bufA[SP(k + 1)] = make_float2(v.z, v.w);
    }
    fft_fill_lut<1>(lut, tid);
    __syncthreads();
    fft_stages<1, false>(bufA, bufB, lut, tid);
    int p = blockIdx.x >> 10;
    int y = blockIdx.x & 1023;
    int oy = (y + 512) & 1023;
    float* p0 = psf + (((size_t)(2 * p) << 20) + ((size_t)oy << 10));
    float* p1 = p0 + (1u << 20);
    const float sc = 1.0f / 1024.0f;
    ull e0 = 0, e1 = 0;
    for (int k = tid; k < 1024; k += 256) {
        float2 v = bufB[SP(k)];
        float re = v.x * sc; re = (re < THRESH) ? 0.0f : re;
        float im = v.y * sc; im = (im < THRESH) ? 0.0f : im;
        int ox = (k + 512) & 1023;
        p0[ox] = re;
        p1[ox] = im;
        unsigned int idx = ((unsigned int)oy << 10) | (unsigned int)ox;
        ull c0 = ((ull)__float_as_uint(re) << 32) | (ull)(0xFFFFFFFFu - idx);
        ull c1 = ((ull)__float_as_uint(im) << 32) | (ull)(0xFFFFFFFFu - idx);
        e0 = c0 > e0 ? c0 : e0;
        e1 = c1 > e1 ? c1 : e1;
    }
    red[tid] = e0;
    __syncthreads();
    for (int s2 = 128; s2 > 0; s2 >>= 1) {
        if (tid < s2) { ull a = red[tid], b = red[tid + s2]; red[tid] = a > b ? a : b; }
        __syncthreads();
    }
    if (tid == 0) bm[((size_t)(2 * p) << 10) + y] = red[0];
    __syncthreads();
    red[tid] = e1;
    __syncthreads();
    for (int s2 = 128; s2 > 0; s2 >>= 1) {
        if (tid < s2) { ull a = red[tid], b = red[tid + s2]; red[tid] = a > b ? a : b; }
        __syncthreads();
    }
    if (tid == 0) bm[((size_t)(2 * p + 1) << 10) + y] = red[0];
}

// ---------------------------------------------------------------------------
// In-place square transpose, 32x32 tile pairs, per plane (grid.y = plane)
// ---------------------------------------------------------------------------
__global__ __launch_bounds__(256) void transpose_kernel(float2* __restrict__ A) {
    __shared__ float2 ta[32][33];
    __shared__ float2 tb[32][33];
    float2* P = A + ((size_t)blockIdx.y << 20);
    int r = blockIdx.x, bi = 0;
    while (r >= 32 - bi) { r -= 32 - bi; ++bi; }
    int bj = bi + r;
    int tx = threadIdx.x & 31, ty = threadIdx.x >> 5;
    for (int yy = ty; yy < 32; yy += 8) {
        ta[yy][tx] = P[(size_t)(bi * 32 + yy) * SS + bj * 32 + tx];
        tb[yy][tx] = P[(size_t)(bj * 32 + yy) * SS + bi * 32 + tx];
    }
    __syncthreads();
    for (int yy = ty; yy < 32; yy += 8) {
        P[(size_t)(bi * 32 + yy) * SS + bj * 32 + tx] = tb[tx][yy];
        P[(size_t)(bj * 32 + yy) * SS + bi * 32 + tx] = ta[tx][yy];
    }
}

// ---------------------------------------------------------------------------
// Per-channel argmax finish (reduce 1024 per-block maxima) + crop 41x41
// (dynamic_slice clamp semantics) + normalize. One block per channel.
// ---------------------------------------------------------------------------
__global__ __launch_bounds__(256) void crop_kernel(
        const float* __restrict__ psf, const ull* __restrict__ bm,
        float* __restrict__ out) {
    int c = blockIdx.x;
    __shared__ ull rmax[256];
    __shared__ float red[256];
    int tid = threadIdx.x;
    ull e = 0;
    for (int i = tid; i < 1024; i += 256) {
        ull v = bm[((size_t)c << 10) + i];
        e = v > e ? v : e;
    }
    rmax[tid] = e;
    __syncthreads();
    for (int s2 = 128; s2 > 0; s2 >>= 1) {
        if (tid < s2) { ull a = rmax[tid], b = rmax[tid + s2]; rmax[tid] = a > b ? a : b; }
        __syncthreads();
    }
    unsigned int bidx = 0xFFFFFFFFu - (unsigned int)(rmax[0] & 0xFFFFFFFFull);
    int row = (int)(bidx >> 10), col = (int)(bidx & 1023);
    int r0 = row - 20; if (r0 < 0) r0 = 0; if (r0 > SS - 41) r0 = SS - 41;
    int c0 = col - 20; if (c0 < 0) c0 = 0; if (c0 > SS - 41) c0 = SS - 41;
    const float* p = psf + ((size_t)c << 20);
    float local = 0.0f;
    for (int i = tid; i < 1681; i += 256) {
        int rr = i / 41, cc = i - rr * 41;
        local += p[(size_t)(r0 + rr) * SS + c0 + cc];
    }
    red[tid] = local;
    __syncthreads();
    for (int s2 = 128; s2 > 0; s2 >>= 1) {
        if (tid < s2) red[tid] += red[tid + s2];
        __syncthreads();
    }
    float inv = 1.0f / red[0];
    for (int i = tid; i < 1681; i += 256) {
        int rr = i / 41, cc = i - rr * 41;
        out[c * 1681 + i] = p[(size_t)(r0 + rr) * SS + c0 + cc] * inv;
    }
}

// ---------------------------------------------------------------------------
extern "C" void kernel_launch(void* const* d_in, const int* in_sizes, int n_in,
                              void* d_out, int out_size, void* d_ws,
                              size_t ws_size, hipStream_t stream) {
    const float* lms = (const float*)d_in[0];
    const float* fuse = (const float*)d_in[1];
    char* ws = (char*)d_ws;
    float2* Zf = (float2*)ws;                                   // 64 MB: 8 planes
    float2* Wb = (float2*)(ws + ((size_t)64 << 20));            // 32 MB: 4 planes
    float* psf = (float*)ws;                                    // 32 MB, reuses Zf
    ull* bm = (ull*)(ws + ((size_t)33 << 20));                  // 64 KB, dead Zf region
    float* outp = (float*)d_out;

    // 1. fused blur + pack + forward row-FFT -> Zf[c][y][kx]
    blur_fft_kernel<<<8192, 256, 0, stream>>>(lms, fuse, Zf);
    // 2. transpose -> Zf[c][kx][y]
    transpose_kernel<<<dim3(528, 8), 256, 0, stream>>>(Zf);
    // 3. fused col-FFT + Wiener + inverse-ky-FFT -> Wb[p][kx][y]
    fft2_wiener_kernel<<<2048, 256, 0, stream>>>(Zf, Wb);
    // 4. transpose -> Wb[p][y][kx]
    transpose_kernel<<<dim3(528, 4), 256, 0, stream>>>(Wb);
    // 5. inverse kx-FFT + shift/threshold/split/block-argmax
    ifft_final_kernel<<<4096, 256, 0, stream>>>(Wb, psf, bm);
    // 6. argmax finish + crop/normalize
    crop_kernel<<<8, 256, 0, stream>>>(psf, bm, outp);
}

// Round 10
// 215.082 us; speedup vs baseline: 1.5698x; 1.0787x over previous
//
#include <hip/hip_runtime.h>
#include <math.h>

#define SS 1024
#define NC 8
#define BWD 170
#define THRESH 1e-4f

typedef unsigned long long ull;

__device__ __forceinline__ float2 cmul(float2 a, float2 b) {
    return make_float2(a.x * b.x - a.y * b.y, a.x * b.y + a.y * b.x);
}

// ---------------------------------------------------------------------------
// XOR bank swizzle for FFT LDS buffers: bijection on [0,1024), mixes bits 4-7
// into bits 0-3 so every Stockham write stage hits 16 distinct bank-pairs
// (the wave64 b64 minimum) while stride-1 reads stay conflict-free.
// (R9 lesson: additive padding broke the reads; XOR preserves them.)
// ---------------------------------------------------------------------------
#define XS(a) ((a) ^ (((a) >> 4) & 15))

// lut[k] = exp(DIRSIGN * 2*pi*i*k/1024), k in [0,768) — HW v_sin/v_cos
// (input in revolutions, args in [0,0.75) need no range reduction).
template <int DIRSIGN>
__device__ __forceinline__ void fft_fill_lut(float2* lut, int tid) {
    for (int i = tid; i < 768; i += 256) {
        float rev = (float)i * (1.0f / 1024.0f);
        float cv = __builtin_amdgcn_cosf(rev);
        float sv = __builtin_amdgcn_sinf(rev);
        lut[i] = make_float2(cv, (float)DIRSIGN * sv);
    }
}

template <int DIRSIGN>
__device__ __forceinline__ void bfly4(const float2 v[4], float2 r[4]) {
    float2 a = v[0], b = v[1], c = v[2], d = v[3];
    float2 apc = make_float2(a.x + c.x, a.y + c.y);
    float2 amc = make_float2(a.x - c.x, a.y - c.y);
    float2 bpd = make_float2(b.x + d.x, b.y + d.y);
    float2 jb  = make_float2(-(b.y - d.y), b.x - d.x);   // i*(b-d)
    r[0] = make_float2(apc.x + bpd.x, apc.y + bpd.y);
    r[2] = make_float2(apc.x - bpd.x, apc.y - bpd.y);
    if (DIRSIGN == -1) {
        r[1] = make_float2(amc.x - jb.x, amc.y - jb.y);
        r[3] = make_float2(amc.x + jb.x, amc.y + jb.y);
    } else {
        r[1] = make_float2(amc.x + jb.x, amc.y + jb.y);
        r[3] = make_float2(amc.x - jb.x, amc.y - jb.y);
    }
}

// ---------------------------------------------------------------------------
// 1024-pt Stockham radix-4, register-resident ends. On entry v[m] holds
// element (tid + 256m); caller must have lut visible (barrier) and A,B free.
// Stages 0-3 go through LDS (XS-swizzled, 1 barrier each); stage 4 (s=256,
// k=0 -> twiddles==1, thread-local I/O) runs in registers. On exit v[r] holds
// final FFT element (tid + 256r). 4 barriers, 4 LDS write+read rounds.
// ---------------------------------------------------------------------------
template <int DIRSIGN, bool CONJ>
__device__ __forceinline__ void fft1024_reg(float2 v[4], float2* A, float2* B,
                                            const float2* lut, int tid) {
    float2* dst = A;
    float2* alt = B;
    #pragma unroll
    for (int t = 0; t < 4; ++t) {
        int s = 1 << (2 * t);
        int k = tid & ~(s - 1);
        float2 r[4];
        bfly4<DIRSIGN>(v, r);
        float2 w1 = lut[k], w2 = lut[2 * k], w3 = lut[3 * k];
        if (CONJ) { w1.y = -w1.y; w2.y = -w2.y; w3.y = -w3.y; }
        int base = tid + 3 * k;
        dst[XS(base)]         = r[0];
        dst[XS(base + s)]     = cmul(r[1], w1);
        dst[XS(base + 2 * s)] = cmul(r[2], w2);
        dst[XS(base + 3 * s)] = cmul(r[3], w3);
        __syncthreads();
        v[0] = dst[XS(tid)];
        v[1] = dst[XS(tid + 256)];
        v[2] = dst[XS(tid + 512)];
        v[3] = dst[XS(tid + 768)];
        float2* tmp = dst; dst = alt; alt = tmp;
    }
    float2 r[4];
    bfly4<DIRSIGN>(v, r);   // stage 4: twiddle-free, thread-local
    v[0] = r[0]; v[1] = r[1]; v[2] = r[2]; v[3] = r[3];
}

// LDS padding for the H-blur row buffers (float units, stride-4 reads)
#define PIDX(r) ((r) + ((r) >> 5))

// ---------------------------------------------------------------------------
// Fused blur + alpha blend + pack + forward row FFT. Block = (channel, row).
// XCD-band swizzle keeps the 7-row V-blur halo in one XCD's L2 (R8: FETCH
// 147->33.5MB). V-blur in registers, H-blur via one LDS row, alpha blend,
// pack Z = lms_e + i*fuse_e into bufA (XS layout), FFT, store from registers.
// ---------------------------------------------------------------------------
__global__ __launch_bounds__(256) void blur_fft_kernel(
        const float* __restrict__ lms, const float* __restrict__ fuse,
        float2* __restrict__ Zf) {
    __shared__ float2 bufA[1024];      // handoff + FFT ping-pong partner
    __shared__ float2 smemB2[1068];    // aliases: rowl/rowf floats, FFT buffer
    __shared__ float2 lut[768];
    float* rowl = (float*)smemB2;      // PIDX(col+3), col -3..1026  (1062 fl)
    float* rowf = rowl + 1068;
    int tid = threadIdx.x;
    int g = blockIdx.x;
    int c = g >> 10;
    int y = (g & 7) * 128 + ((g >> 3) & 127);   // XCD band swizzle
    const float* L = lms + ((size_t)c << 20);
    const float* F = fuse + ((size_t)c << 20);
    int x0 = tid << 2;

    // Gaussian weights (sigma=1, ks=7)
    double e1 = exp(-0.5), e2 = exp(-2.0), e3 = exp(-4.5);
    double sm = 1.0 + 2.0 * (e1 + e2 + e3);
    float w[7] = { (float)(e3 / sm), (float)(e2 / sm), (float)(e1 / sm),
                   (float)(1.0 / sm),
                   (float)(e1 / sm), (float)(e2 / sm), (float)(e3 / sm) };

    bool rowInt = (y >= BWD) && (y <= SS - 1 - BWD);
    bool skipLoads = rowInt && (tid >= 45) && (tid <= 210);
    bool doH = !rowInt || (tid <= 43) || (tid >= 212);

    float4 cl, cf;
    if (skipLoads) {
        cl = *(const float4*)&L[((size_t)y << 10) + x0];
        cf = *(const float4*)&F[((size_t)y << 10) + x0];
    } else {
        float4 lv[7], fv[7];
        #pragma unroll
        for (int r = 0; r < 7; ++r) {
            int gy = y - 3 + r;
            if (gy >= 0 && gy < SS) {
                lv[r] = *(const float4*)&L[((size_t)gy << 10) + x0];
                fv[r] = *(const float4*)&F[((size_t)gy << 10) + x0];
            } else {
                lv[r] = make_float4(0.f, 0.f, 0.f, 0.f);
                fv[r] = make_float4(0.f, 0.f, 0.f, 0.f);
            }
        }
        cl = lv[3]; cf = fv[3];
        #pragma unroll
        for (int j = 0; j < 4; ++j) {
            float a = 0.f, b = 0.f;
            #pragma unroll
            for (int r = 0; r < 7; ++r) {
                a += w[r] * (&lv[r].x)[j];
                b += w[r] * (&fv[r].x)[j];
            }
            rowl[PIDX(3 + x0 + j)] = a;
            rowf[PIDX(3 + x0 + j)] = b;
        }
    }
    if (tid < 3) {
        rowl[PIDX(tid)] = 0.f; rowf[PIDX(tid)] = 0.f;
        rowl[PIDX(1027 + tid)] = 0.f; rowf[PIDX(1027 + tid)] = 0.f;
    }
    fft_fill_lut<-1>(lut, tid);
    __syncthreads();

    float bl[4] = {0.f, 0.f, 0.f, 0.f}, bf[4] = {0.f, 0.f, 0.f, 0.f};
    if (doH) {
        #pragma unroll
        for (int k = 0; k < 4; ++k) {
            float a = 0.f, b = 0.f;
            #pragma unroll
            for (int j = 0; j < 7; ++j) {
                a += w[j] * rowl[PIDX(x0 + k + j)];
                b += w[j] * rowf[PIDX(x0 + k + j)];
            }
            bl[k] = a; bf[k] = b;
        }
    }
    int gyv = (y < BWD) ? y : ((SS - 1 - y) < BWD ? (SS - 1 - y) : -1);
    #pragma unroll
    for (int k = 0; k < 4; ++k) {
        int x = x0 + k;
        int gx = (x < BWD) ? x : ((SS - 1 - x) < BWD ? (SS - 1 - x) : -1);
        int m = gyv > gx ? gyv : gx;
        float a = (m >= 0) ? (float)m / (float)BWD : 1.0f;
        bufA[XS(x)] = make_float2(a * (&cl.x)[k] + (1.0f - a) * bl[k],
                                  a * (&cf.x)[k] + (1.0f - a) * bf[k]);
    }
    __syncthreads();   // bufA handoff ready; rowl/rowf reads done

    float2 v[4];
    #pragma unroll
    for (int m = 0; m < 4; ++m) v[m] = bufA[XS(tid + (m << 8))];
    fft1024_reg<-1, false>(v, smemB2, bufA, lut, tid);

    float2* Zrow = Zf + (((size_t)c << 20) + ((size_t)y << 10));
    #pragma unroll
    for (int r = 0; r < 4; ++r) Zrow[tid + (r << 8)] = v[r];
}

// ---------------------------------------------------------------------------
// Fused second forward FFT + Wiener + first inverse FFT (along ky).
// One block owns a conjugate row pair (u, 1024-u) for a channel pair p:
// 4 forward FFTs (register-loaded from global, results in XS-layout LDS),
// Wiener to registers, 2 inverse FFTs, store Wb[p][u][y] from registers.
// Block i=0 handles self-paired rows {0, 512}.
// ---------------------------------------------------------------------------
__global__ __launch_bounds__(256) void fft2_wiener_kernel(
        const float2* __restrict__ Z, float2* __restrict__ Wb) {
    __shared__ float2 resbuf[4][1024];
    __shared__ float2 scratch[1024];
    __shared__ float2 lut[768];
    int tid = threadIdx.x;
    int p = blockIdx.x >> 9;          // channel pair 0..3
    int i = blockIdx.x & 511;
    int rows[2];
    rows[0] = (i == 0) ? 0 : i;
    rows[1] = (i == 0) ? 512 : 1024 - i;
    bool selfp = (i == 0);

    fft_fill_lut<-1>(lut, tid);
    __syncthreads();   // lut visible before first butterfly

    // combo = rowIdx*2 + ch; register loads (b64, coalesced per instruction)
    float2 v[4], nv[4];
    {
        const float2* g0 = Z + (((size_t)(2 * p) << 20) +
                                ((size_t)rows[0] << 10));
        #pragma unroll
        for (int m = 0; m < 4; ++m) v[m] = g0[tid + (m << 8)];
    }
    #pragma unroll
    for (int combo = 0; combo < 4; ++combo) {
        if (combo < 3) {
            int nr = (combo + 1) >> 1, nc = (combo + 1) & 1;
            const float2* gn = Z + (((size_t)(2 * p + nc) << 20) +
                                    ((size_t)rows[nr] << 10));
            #pragma unroll
            for (int m = 0; m < 4; ++m) nv[m] = gn[tid + (m << 8)];
        }
        fft1024_reg<-1, false>(v, scratch, resbuf[combo], lut, tid);
        #pragma unroll
        for (int r = 0; r < 4; ++r)
            resbuf[combo][XS(tid + (r << 8))] = v[r];
        if (combo < 3) {
            #pragma unroll
            for (int m = 0; m < 4; ++m) v[m] = nv[m];
        }
    }
    __syncthreads();   // all forward results visible

    // Wiener to registers
    float2 gout[2][4];
    #pragma unroll
    for (int o = 0; o < 2; ++o) {
        int u = rows[o];
        int po = selfp ? o : (1 - o);      // partner row's slot base
        float cu = __builtin_amdgcn_cosf((float)u * (1.0f / 1024.0f));
        float c2u = 2.0f * cu * cu - 1.0f;
        float hu = 2.0f + 2.0f * cu;
        #pragma unroll
        for (int j = 0; j < 4; ++j) {
            int vv = tid + (j << 8);
            int vn = (1024 - vv) & 1023;
            float cv = __builtin_amdgcn_cosf((float)vv * (1.0f / 1024.0f));
            float c2v = 2.0f * cv * cv - 1.0f;
            float hv = 2.0f + 2.0f * cv;
            float grad = (2.0f - 2.0f * c2v) * hu * hu +
                         (2.0f - 2.0f * c2u) * hv * hv;
            float regs = 5.0f + 5.0f * grad;
            float G0x, G0y, G1x, G1y;
            #pragma unroll
            for (int c = 0; c < 2; ++c) {
                float2 a = resbuf[o * 2 + c][XS(vv)];
                float2 b = resbuf[po * 2 + c][XS(vn)];
                float Lx = 0.5f * (a.x + b.x), Ly = 0.5f * (a.y - b.y);
                float Fx = 0.5f * (a.y + b.y), Fy = -0.5f * (a.x - b.x);
                float inv = 1.0f / (Fx * Fx + Fy * Fy + regs);
                float nx = (Fx * Lx + Fy * Ly) * inv;   // conj(F)*L
                float ny = (Fx * Ly - Fy * Lx) * inv;
                if (c == 0) { G0x = nx; G0y = ny; } else { G1x = nx; G1y = ny; }
            }
            gout[o][j] = make_float2(G0x - G1y, G0y + G1x);
        }
    }
    __syncthreads();   // all resbuf reads complete; buffers reusable

    // inverse FFT along ky for both owned rows; store from registers
    const float isc = 1.0f / 1024.0f;
    #pragma unroll
    for (int o = 0; o < 2; ++o) {
        float2 iv[4];
        #pragma unroll
        for (int j = 0; j < 4; ++j) iv[j] = gout[o][j];   // already tid+256j
        fft1024_reg<1, true>(iv, scratch, resbuf[o], lut, tid);
        float2* go = Wb + (((size_t)p << 20) + ((size_t)rows[o] << 10));
        #pragma unroll
        for (int r = 0; r < 4; ++r)
            go[tid + (r << 8)] = make_float2(iv[r].x * isc, iv[r].y * isc);
    }
}

// ---------------------------------------------------------------------------
// Final inverse pass: register-loaded row FFT, fused 1/N scale + fftshift +
// threshold + split into two real psf planes + per-block argmax to a PRIVATE
// slot bm[channel*1024 + row] (R5 lesson: no hot same-address atomics).
// ---------------------------------------------------------------------------
__global__ __launch_bounds__(256) void ifft_final_kernel(
        const float2* __restrict__ Wd, float* __restrict__ psf,
        ull* __restrict__ bm) {
    __shared__ float2 bufA[1024];
    __shared__ float2 bufB[1024];
    __shared__ float2 lut[768];
    __shared__ ull red[256];
    int tid = threadIdx.x;
    const float2* g = Wd + ((size_t)blockIdx.x << 10);
    float2 v[4];
    #pragma unroll
    for (int m = 0; m < 4; ++m) v[m] = g[tid + (m << 8)];
    fft_fill_lut<1>(lut, tid);
    __syncthreads();
    fft1024_reg<1, false>(v, bufA, bufB, lut, tid);

    int p = blockIdx.x >> 10;
    int y = blockIdx.x & 1023;
    int oy = (y + 512) & 1023;
    float* p0 = psf + (((size_t)(2 * p) << 20) + ((size_t)oy << 10));
    float* p1 = p0 + (1u << 20);
    const float sc = 1.0f / 1024.0f;
    ull e0 = 0, e1 = 0;
    #pragma unroll
    for (int r = 0; r < 4; ++r) {
        int k = tid + (r << 8);
        float re = v[r].x * sc; re = (re < THRESH) ? 0.0f : re;
        float im = v[r].y * sc; im = (im < THRESH) ? 0.0f : im;
        int ox = (k + 512) & 1023;
        p0[ox] = re;
        p1[ox] = im;
        unsigned int idx = ((unsigned int)oy << 10) | (unsigned int)ox;
        ull c0 = ((ull)__float_as_uint(re) << 32) | (ull)(0xFFFFFFFFu - idx);
        ull c1 = ((ull)__float_as_uint(im) << 32) | (ull)(0xFFFFFFFFu - idx);
        e0 = c0 > e0 ? c0 : e0;
        e1 = c1 > e1 ? c1 : e1;
    }
    red[tid] = e0;
    __syncthreads();
    for (int s2 = 128; s2 > 0; s2 >>= 1) {
        if (tid < s2) { ull a = red[tid], b = red[tid + s2]; red[tid] = a > b ? a : b; }
        __syncthreads();
    }
    if (tid == 0) bm[((size_t)(2 * p) << 10) + y] = red[0];
    __syncthreads();
    red[tid] = e1;
    __syncthreads();
    for (int s2 = 128; s2 > 0; s2 >>= 1) {
        if (tid < s2) { ull a = red[tid], b = red[tid + s2]; red[tid] = a > b ? a : b; }
        __syncthreads();
    }
    if (tid == 0) bm[((size_t)(2 * p + 1) << 10) + y] = red[0];
}

// ---------------------------------------------------------------------------
// In-place square transpose, 32x32 tile pairs, per plane (grid.y = plane)
// ---------------------------------------------------------------------------
__global__ __launch_bounds__(256) void transpose_kernel(float2* __restrict__ A) {
    __shared__ float2 ta[32][33];
    __shared__ float2 tb[32][33];
    float2* P = A + ((size_t)blockIdx.y << 20);
    int r = blockIdx.x, bi = 0;
    while (r >= 32 - bi) { r -= 32 - bi; ++bi; }
    int bj = bi + r;
    int tx = threadIdx.x & 31, ty = threadIdx.x >> 5;
    for (int yy = ty; yy < 32; yy += 8) {
        ta[yy][tx] = P[(size_t)(bi * 32 + yy) * SS + bj * 32 + tx];
        tb[yy][tx] = P[(size_t)(bj * 32 + yy) * SS + bi * 32 + tx];
    }
    __syncthreads();
    for (int yy = ty; yy < 32; yy += 8) {
        P[(size_t)(bi * 32 + yy) * SS + bj * 32 + tx] = tb[tx][yy];
        P[(size_t)(bj * 32 + yy) * SS + bi * 32 + tx] = ta[tx][yy];
    }
}

// ---------------------------------------------------------------------------
// Per-channel argmax finish (reduce 1024 per-block maxima) + crop 41x41
// (dynamic_slice clamp semantics) + normalize. One block per channel.
// ---------------------------------------------------------------------------
__global__ __launch_bounds__(256) void crop_kernel(
        const float* __restrict__ psf, const ull* __restrict__ bm,
        float* __restrict__ out) {
    int c = blockIdx.x;
    __shared__ ull rmax[256];
    __shared__ float red[256];
    int tid = threadIdx.x;
    ull e = 0;
    for (int i = tid; i < 1024; i += 256) {
        ull v = bm[((size_t)c << 10) + i];
        e = v > e ? v : e;
    }
    rmax[tid] = e;
    __syncthreads();
    for (int s2 = 128; s2 > 0; s2 >>= 1) {
        if (tid < s2) { ull a = rmax[tid], b = rmax[tid + s2]; rmax[tid] = a > b ? a : b; }
        __syncthreads();
    }
    unsigned int bidx = 0xFFFFFFFFu - (unsigned int)(rmax[0] & 0xFFFFFFFFull);
    int row = (int)(bidx >> 10), col = (int)(bidx & 1023);
    int r0 = row - 20; if (r0 < 0) r0 = 0; if (r0 > SS - 41) r0 = SS - 41;
    int c0 = col - 20; if (c0 < 0) c0 = 0; if (c0 > SS - 41) c0 = SS - 41;
    const float* p = psf + ((size_t)c << 20);
    float local = 0.0f;
    for (int i = tid; i < 1681; i += 256) {
        int rr = i / 41, cc = i - rr * 41;
        local += p[(size_t)(r0 + rr) * SS + c0 + cc];
    }
    red[tid] = local;
    __syncthreads();
    for (int s2 = 128; s2 > 0; s2 >>= 1) {
        if (tid < s2) red[tid] += red[tid + s2];
        __syncthreads();
    }
    float inv = 1.0f / red[0];
    for (int i = tid; i < 1681; i += 256) {
        int rr = i / 41, cc = i - rr * 41;
        out[c * 1681 + i] = p[(size_t)(r0 + rr) * SS + c0 + cc] * inv;
    }
}

// ---------------------------------------------------------------------------
extern "C" void kernel_launch(void* const* d_in, const int* in_sizes, int n_in,
                              void* d_out, int out_size, void* d_ws,
                              size_t ws_size, hipStream_t stream) {
    const float* lms = (const float*)d_in[0];
    const float* fuse = (const float*)d_in[1];
    char* ws = (char*)d_ws;
    float2* Zf = (float2*)ws;                                   // 64 MB: 8 planes
    float2* Wb = (float2*)(ws + ((size_t)64 << 20));            // 32 MB: 4 planes
    float* psf = (float*)ws;                                    // 32 MB, reuses Zf
    ull* bm = (ull*)(ws + ((size_t)33 << 20));                  // 64 KB, dead Zf region
    float* outp = (float*)d_out;

    // 1. fused blur + pack + forward row-FFT -> Zf[c][y][kx]
    blur_fft_kernel<<<8192, 256, 0, stream>>>(lms, fuse, Zf);
    // 2. transpose -> Zf[c][kx][y]
    transpose_kernel<<<dim3(528, 8), 256, 0, stream>>>(Zf);
    // 3. fused col-FFT + Wiener + inverse-ky-FFT -> Wb[p][kx][y]
    fft2_wiener_kernel<<<2048, 256, 0, stream>>>(Zf, Wb);
    // 4. transpose -> Wb[p][y][kx]
    transpose_kernel<<<dim3(528, 4), 256, 0, stream>>>(Wb);
    // 5. inverse kx-FFT + shift/threshold/split/block-argmax
    ifft_final_kernel<<<4096, 256, 0, stream>>>(Wb, psf, bm);
    // 6. argmax finish + crop/normalize
    crop_kernel<<<8, 256, 0, stream>>>(psf, bm, outp);
}

// Round 11
// 208.427 us; speedup vs baseline: 1.6199x; 1.0319x over previous
//
#include <hip/hip_runtime.h>
#include <math.h>

#define SS 1024
#define NC 8
#define BWD 170
#define THRESH 1e-4f

typedef unsigned long long ull;

__device__ __forceinline__ float2 cmul(float2 a, float2 b) {
    return make_float2(a.x * b.x - a.y * b.y, a.x * b.y + a.y * b.x);
}

// ---------------------------------------------------------------------------
// XOR bank swizzle for FFT LDS buffers: bijection on [0,1024), mixes bits 4-7
// into bits 0-3 so every Stockham write stage hits 16 distinct bank-pairs
// while stride-1 reads stay conflict-free. (R9: additive padding broke reads.)
// ---------------------------------------------------------------------------
#define XS(a) ((a) ^ (((a) >> 4) & 15))

template <int DIR>
__device__ __forceinline__ void bfly4(const float2 v[4], float2 r[4]) {
    float2 a = v[0], b = v[1], c = v[2], d = v[3];
    float2 apc = make_float2(a.x + c.x, a.y + c.y);
    float2 amc = make_float2(a.x - c.x, a.y - c.y);
    float2 bpd = make_float2(b.x + d.x, b.y + d.y);
    float2 jb  = make_float2(-(b.y - d.y), b.x - d.x);   // i*(b-d)
    r[0] = make_float2(apc.x + bpd.x, apc.y + bpd.y);
    r[2] = make_float2(apc.x - bpd.x, apc.y - bpd.y);
    if (DIR == -1) {
        r[1] = make_float2(amc.x - jb.x, amc.y - jb.y);
        r[3] = make_float2(amc.x + jb.x, amc.y + jb.y);
    } else {
        r[1] = make_float2(amc.x + jb.x, amc.y + jb.y);
        r[3] = make_float2(amc.x - jb.x, amc.y - jb.y);
    }
}

// ---------------------------------------------------------------------------
// 1024-pt Stockham radix-4, register-resident ends, INLINE twiddles.
// w1 = exp(DIR*2pi*i*k/1024) via HW sincos (revolutions, validated R9);
// w2 = w1^2, w3 = w1*w2 — no LUT, no lut-fill barrier, 12 fewer ds_read/FFT.
// On entry v[m] holds element (tid+256m); A,B are free 1024-float2 buffers.
// Stages 0-3 via LDS (XS swizzle, 1 barrier each); stage 4 (s=256, k=0,
// twiddle-free, thread-local) in registers. On exit v[r] = element tid+256r.
// ---------------------------------------------------------------------------
template <int DIR>
__device__ __forceinline__ void fft1024_reg(float2 v[4], float2* A, float2* B,
                                            int tid) {
    float2* dst = A;
    float2* alt = B;
    #pragma unroll
    for (int t = 0; t < 4; ++t) {
        int s = 1 << (2 * t);
        int k = tid & ~(s - 1);
        float2 r[4];
        bfly4<DIR>(v, r);
        float rev = (float)k * (1.0f / 1024.0f);
        float2 w1 = make_float2(__builtin_amdgcn_cosf(rev),
                                (float)DIR * __builtin_amdgcn_sinf(rev));
        float2 w2 = cmul(w1, w1);
        float2 w3 = cmul(w2, w1);
        int base = tid + 3 * k;
        dst[XS(base)]         = r[0];
        dst[XS(base + s)]     = cmul(r[1], w1);
        dst[XS(base + 2 * s)] = cmul(r[2], w2);
        dst[XS(base + 3 * s)] = cmul(r[3], w3);
        __syncthreads();
        v[0] = dst[XS(tid)];
        v[1] = dst[XS(tid + 256)];
        v[2] = dst[XS(tid + 512)];
        v[3] = dst[XS(tid + 768)];
        float2* tmp = dst; dst = alt; alt = tmp;
    }
    float2 r[4];
    bfly4<DIR>(v, r);   // stage 4: twiddle-free, thread-local
    v[0] = r[0]; v[1] = r[1]; v[2] = r[2]; v[3] = r[3];
}

// LDS padding for the H-blur row buffers (float units, stride-4 reads)
#define PIDX(r) ((r) + ((r) >> 5))

// ---------------------------------------------------------------------------
// Fused blur + alpha blend + pack + forward row FFT. Block = (channel, row).
// XCD-band swizzle keeps the 7-row V-blur halo in one XCD's L2 (R8: FETCH
// 147->33.5MB). V-blur in registers, H-blur via one LDS row, alpha blend,
// pack Z = lms_e + i*fuse_e into bufA (XS layout), FFT, store from registers.
// ---------------------------------------------------------------------------
__global__ __launch_bounds__(256) void blur_fft_kernel(
        const float* __restrict__ lms, const float* __restrict__ fuse,
        float2* __restrict__ Zf) {
    __shared__ float2 bufA[1024];      // handoff + FFT ping-pong partner
    __shared__ float2 smemB2[1068];    // aliases: rowl/rowf floats, FFT buffer
    float* rowl = (float*)smemB2;      // PIDX(col+3), col -3..1026
    float* rowf = rowl + 1068;
    int tid = threadIdx.x;
    int g = blockIdx.x;
    int c = g >> 10;
    int y = (g & 7) * 128 + ((g >> 3) & 127);   // XCD band swizzle
    const float* L = lms + ((size_t)c << 20);
    const float* F = fuse + ((size_t)c << 20);
    int x0 = tid << 2;

    // Gaussian weights (sigma=1, ks=7)
    double e1 = exp(-0.5), e2 = exp(-2.0), e3 = exp(-4.5);
    double sm = 1.0 + 2.0 * (e1 + e2 + e3);
    float w[7] = { (float)(e3 / sm), (float)(e2 / sm), (float)(e1 / sm),
                   (float)(1.0 / sm),
                   (float)(e1 / sm), (float)(e2 / sm), (float)(e3 / sm) };

    bool rowInt = (y >= BWD) && (y <= SS - 1 - BWD);
    bool skipLoads = rowInt && (tid >= 45) && (tid <= 210);
    bool doH = !rowInt || (tid <= 43) || (tid >= 212);

    float4 cl, cf;
    if (skipLoads) {
        cl = *(const float4*)&L[((size_t)y << 10) + x0];
        cf = *(const float4*)&F[((size_t)y << 10) + x0];
    } else {
        float4 lv[7], fv[7];
        #pragma unroll
        for (int r = 0; r < 7; ++r) {
            int gy = y - 3 + r;
            if (gy >= 0 && gy < SS) {
                lv[r] = *(const float4*)&L[((size_t)gy << 10) + x0];
                fv[r] = *(const float4*)&F[((size_t)gy << 10) + x0];
            } else {
                lv[r] = make_float4(0.f, 0.f, 0.f, 0.f);
                fv[r] = make_float4(0.f, 0.f, 0.f, 0.f);
            }
        }
        cl = lv[3]; cf = fv[3];
        #pragma unroll
        for (int j = 0; j < 4; ++j) {
            float a = 0.f, b = 0.f;
            #pragma unroll
            for (int r = 0; r < 7; ++r) {
                a += w[r] * (&lv[r].x)[j];
                b += w[r] * (&fv[r].x)[j];
            }
            rowl[PIDX(3 + x0 + j)] = a;
            rowf[PIDX(3 + x0 + j)] = b;
        }
    }
    if (tid < 3) {
        rowl[PIDX(tid)] = 0.f; rowf[PIDX(tid)] = 0.f;
        rowl[PIDX(1027 + tid)] = 0.f; rowf[PIDX(1027 + tid)] = 0.f;
    }
    __syncthreads();

    float bl[4] = {0.f, 0.f, 0.f, 0.f}, bf[4] = {0.f, 0.f, 0.f, 0.f};
    if (doH) {
        #pragma unroll
        for (int k = 0; k < 4; ++k) {
            float a = 0.f, b = 0.f;
            #pragma unroll
            for (int j = 0; j < 7; ++j) {
                a += w[j] * rowl[PIDX(x0 + k + j)];
                b += w[j] * rowf[PIDX(x0 + k + j)];
            }
            bl[k] = a; bf[k] = b;
        }
    }
    int gyv = (y < BWD) ? y : ((SS - 1 - y) < BWD ? (SS - 1 - y) : -1);
    #pragma unroll
    for (int k = 0; k < 4; ++k) {
        int x = x0 + k;
        int gx = (x < BWD) ? x : ((SS - 1 - x) < BWD ? (SS - 1 - x) : -1);
        int m = gyv > gx ? gyv : gx;
        float a = (m >= 0) ? (float)m / (float)BWD : 1.0f;
        bufA[XS(x)] = make_float2(a * (&cl.x)[k] + (1.0f - a) * bl[k],
                                  a * (&cf.x)[k] + (1.0f - a) * bf[k]);
    }
    __syncthreads();   // bufA handoff ready; rowl/rowf reads done

    float2 v[4];
    #pragma unroll
    for (int m = 0; m < 4; ++m) v[m] = bufA[XS(tid + (m << 8))];
    fft1024_reg<-1>(v, smemB2, bufA, tid);

    float2* Zrow = Zf + (((size_t)c << 20) + ((size_t)y << 10));
    #pragma unroll
    for (int r = 0; r < 4; ++r) Zrow[tid + (r << 8)] = v[r];
}

// ---------------------------------------------------------------------------
// Fused second forward FFT + Wiener + first inverse FFT (along ky).
// One block owns a conjugate row pair (u, 1024-u) for a channel pair p:
// 4 forward FFTs (register-loaded, results in XS-layout LDS), Wiener to
// registers, 2 inverse FFTs, store Wb[p][u][y] from registers.
// Block i=0 handles self-paired rows {0, 512}.
// ---------------------------------------------------------------------------
__global__ __launch_bounds__(256) void fft2_wiener_kernel(
        const float2* __restrict__ Z, float2* __restrict__ Wb) {
    __shared__ float2 resbuf[4][1024];
    __shared__ float2 scratch[1024];
    int tid = threadIdx.x;
    int p = blockIdx.x >> 9;          // channel pair 0..3
    int i = blockIdx.x & 511;
    int rows[2];
    rows[0] = (i == 0) ? 0 : i;
    rows[1] = (i == 0) ? 512 : 1024 - i;
    bool selfp = (i == 0);

    // combo = rowIdx*2 + ch; register loads (b64, coalesced per instruction)
    float2 v[4], nv[4];
    {
        const float2* g0 = Z + (((size_t)(2 * p) << 20) +
                                ((size_t)rows[0] << 10));
        #pragma unroll
        for (int m = 0; m < 4; ++m) v[m] = g0[tid + (m << 8)];
    }
    #pragma unroll
    for (int combo = 0; combo < 4; ++combo) {
        if (combo < 3) {
            int nr = (combo + 1) >> 1, nc = (combo + 1) & 1;
            const float2* gn = Z + (((size_t)(2 * p + nc) << 20) +
                                    ((size_t)rows[nr] << 10));
            #pragma unroll
            for (int m = 0; m < 4; ++m) nv[m] = gn[tid + (m << 8)];
        }
        fft1024_reg<-1>(v, scratch, resbuf[combo], tid);
        #pragma unroll
        for (int r = 0; r < 4; ++r)
            resbuf[combo][XS(tid + (r << 8))] = v[r];
        if (combo < 3) {
            #pragma unroll
            for (int m = 0; m < 4; ++m) v[m] = nv[m];
        }
    }
    __syncthreads();   // all forward results visible

    // Wiener to registers
    float2 gout[2][4];
    #pragma unroll
    for (int o = 0; o < 2; ++o) {
        int u = rows[o];
        int po = selfp ? o : (1 - o);      // partner row's slot base
        float cu = __builtin_amdgcn_cosf((float)u * (1.0f / 1024.0f));
        float c2u = 2.0f * cu * cu - 1.0f;
        float hu = 2.0f + 2.0f * cu;
        #pragma unroll
        for (int j = 0; j < 4; ++j) {
            int vv = tid + (j << 8);
            int vn = (1024 - vv) & 1023;
            float cv = __builtin_amdgcn_cosf((float)vv * (1.0f / 1024.0f));
            float c2v = 2.0f * cv * cv - 1.0f;
            float hv = 2.0f + 2.0f * cv;
            float grad = (2.0f - 2.0f * c2v) * hu * hu +
                         (2.0f - 2.0f * c2u) * hv * hv;
            float regs = 5.0f + 5.0f * grad;
            float G0x, G0y, G1x, G1y;
            #pragma unroll
            for (int c = 0; c < 2; ++c) {
                float2 a = resbuf[o * 2 + c][XS(vv)];
                float2 b = resbuf[po * 2 + c][XS(vn)];
                float Lx = 0.5f * (a.x + b.x), Ly = 0.5f * (a.y - b.y);
                float Fx = 0.5f * (a.y + b.y), Fy = -0.5f * (a.x - b.x);
                float inv = 1.0f / (Fx * Fx + Fy * Fy + regs);
                float nx = (Fx * Lx + Fy * Ly) * inv;   // conj(F)*L
                float ny = (Fx * Ly - Fy * Lx) * inv;
                if (c == 0) { G0x = nx; G0y = ny; } else { G1x = nx; G1y = ny; }
            }
            gout[o][j] = make_float2(G0x - G1y, G0y + G1x);
        }
    }
    __syncthreads();   // all resbuf reads complete; buffers reusable

    // inverse FFT along ky for both owned rows; store from registers
    const float isc = 1.0f / 1024.0f;
    #pragma unroll
    for (int o = 0; o < 2; ++o) {
        float2 iv[4];
        #pragma unroll
        for (int j = 0; j < 4; ++j) iv[j] = gout[o][j];   // already tid+256j
        fft1024_reg<1>(iv, scratch, resbuf[o], tid);
        float2* go = Wb + (((size_t)p << 20) + ((size_t)rows[o] << 10));
        #pragma unroll
        for (int r = 0; r < 4; ++r)
            go[tid + (r << 8)] = make_float2(iv[r].x * isc, iv[r].y * isc);
    }
}

// ---------------------------------------------------------------------------
// Final inverse pass: register-loaded row FFT, fused 1/N scale + fftshift +
// threshold + split into two real psf planes + per-block argmax (wave-shuffle
// reduced) to a PRIVATE slot bm[channel*1024 + row] (R5: no hot atomics).
// ---------------------------------------------------------------------------
__global__ __launch_bounds__(256) void ifft_final_kernel(
        const float2* __restrict__ Wd, float* __restrict__ psf,
        ull* __restrict__ bm) {
    __shared__ float2 bufA[1024];
    __shared__ float2 bufB[1024];
    __shared__ ull red0[4];
    __shared__ ull red1[4];
    int tid = threadIdx.x;
    const float2* g = Wd + ((size_t)blockIdx.x << 10);
    float2 v[4];
    #pragma unroll
    for (int m = 0; m < 4; ++m) v[m] = g[tid + (m << 8)];
    fft1024_reg<1>(v, bufA, bufB, tid);

    int p = blockIdx.x >> 10;
    int y = blockIdx.x & 1023;
    int oy = (y + 512) & 1023;
    float* p0 = psf + (((size_t)(2 * p) << 20) + ((size_t)oy << 10));
    float* p1 = p0 + (1u << 20);
    const float sc = 1.0f / 1024.0f;
    ull e0 = 0, e1 = 0;
    #pragma unroll
    for (int r = 0; r < 4; ++r) {
        int k = tid + (r << 8);
        float re = v[r].x * sc; re = (re < THRESH) ? 0.0f : re;
        float im = v[r].y * sc; im = (im < THRESH) ? 0.0f : im;
        int ox = (k + 512) & 1023;
        p0[ox] = re;
        p1[ox] = im;
        unsigned int idx = ((unsigned int)oy << 10) | (unsigned int)ox;
        ull c0 = ((ull)__float_as_uint(re) << 32) | (ull)(0xFFFFFFFFu - idx);
        ull c1 = ((ull)__float_as_uint(im) << 32) | (ull)(0xFFFFFFFFu - idx);
        e0 = c0 > e0 ? c0 : e0;
        e1 = c1 > e1 ? c1 : e1;
    }
    #pragma unroll
    for (int off = 32; off > 0; off >>= 1) {
        ull o0 = __shfl_down(e0, off);
        ull o1 = __shfl_down(e1, off);
        e0 = o0 > e0 ? o0 : e0;
        e1 = o1 > e1 ? o1 : e1;
    }
    if ((tid & 63) == 0) { red0[tid >> 6] = e0; red1[tid >> 6] = e1; }
    __syncthreads();
    if (tid == 0) {
        ull m0 = red0[0], m1 = red1[0];
        #pragma unroll
        for (int i2 = 1; i2 < 4; ++i2) {
            m0 = red0[i2] > m0 ? red0[i2] : m0;
            m1 = red1[i2] > m1 ? red1[i2] : m1;
        }
        bm[((size_t)(2 * p) << 10) + y] = m0;
        bm[((size_t)(2 * p + 1) << 10) + y] = m1;
    }
}

// ---------------------------------------------------------------------------
// In-place square transpose, 32x32 float2 tile pairs, float4-vectorized
// global I/O (2 float2 per lane), per plane (grid.y = plane).
// ---------------------------------------------------------------------------
__global__ __launch_bounds__(256) void transpose_kernel(float2* __restrict__ A) {
    __shared__ float2 ta[32][33];
    __shared__ float2 tb[32][33];
    float2* P = A + ((size_t)blockIdx.y << 20);
    int r = blockIdx.x, bi = 0;
    while (r >= 32 - bi) { r -= 32 - bi; ++bi; }
    int bj = bi + r;
    int tx = threadIdx.x & 15;     // float4 index (covers 2 float2 cols)
    int ty = threadIdx.x >> 4;     // 16 rows per iteration
    #pragma unroll
    for (int yy0 = 0; yy0 < 32; yy0 += 16) {
        int yy = yy0 + ty;
        float4 va = *(const float4*)&P[(size_t)(bi * 32 + yy) * SS + bj * 32 + 2 * tx];
        float4 vb = *(const float4*)&P[(size_t)(bj * 32 + yy) * SS + bi * 32 + 2 * tx];
        ta[yy][2 * tx]     = make_float2(va.x, va.y);
        ta[yy][2 * tx + 1] = make_float2(va.z, va.w);
        tb[yy][2 * tx]     = make_float2(vb.x, vb.y);
        tb[yy][2 * tx + 1] = make_float2(vb.z, vb.w);
    }
    __syncthreads();
    #pragma unroll
    for (int yy0 = 0; yy0 < 32; yy0 += 16) {
        int yy = yy0 + ty;
        float2 a0 = tb[2 * tx][yy], a1 = tb[2 * tx + 1][yy];
        *(float4*)&P[(size_t)(bi * 32 + yy) * SS + bj * 32 + 2 * tx] =
            make_float4(a0.x, a0.y, a1.x, a1.y);
        float2 b0 = ta[2 * tx][yy], b1 = ta[2 * tx + 1][yy];
        *(float4*)&P[(size_t)(bj * 32 + yy) * SS + bi * 32 + 2 * tx] =
            make_float4(b0.x, b0.y, b1.x, b1.y);
    }
}

// ---------------------------------------------------------------------------
// Per-channel argmax finish (reduce 1024 per-block maxima) + crop 41x41
// (dynamic_slice clamp semantics) + normalize. One block per channel.
// ---------------------------------------------------------------------------
__global__ __launch_bounds__(256) void crop_kernel(
        const float* __restrict__ psf, const ull* __restrict__ bm,
        float* __restrict__ out) {
    int c = blockIdx.x;
    __shared__ ull rmax[256];
    __shared__ float red[256];
    int tid = threadIdx.x;
    ull e = 0;
    for (int i = tid; i < 1024; i += 256) {
        ull v = bm[((size_t)c << 10) + i];
        e = v > e ? v : e;
    }
    rmax[tid] = e;
    __syncthreads();
    for (int s2 = 128; s2 > 0; s2 >>= 1) {
        if (tid < s2) { ull a = rmax[tid], b = rmax[tid + s2]; rmax[tid] = a > b ? a : b; }
        __syncthreads();
    }
    unsigned int bidx = 0xFFFFFFFFu - (unsigned int)(rmax[0] & 0xFFFFFFFFull);
    int row = (int)(bidx >> 10), col = (int)(bidx & 1023);
    int r0 = row - 20; if (r0 < 0) r0 = 0; if (r0 > SS - 41) r0 = SS - 41;
    int c0 = col - 20; if (c0 < 0) c0 = 0; if (c0 > SS - 41) c0 = SS - 41;
    const float* p = psf + ((size_t)c << 20);
    float local = 0.0f;
    for (int i = tid; i < 1681; i += 256) {
        int rr = i / 41, cc = i - rr * 41;
        local += p[(size_t)(r0 + rr) * SS + c0 + cc];
    }
    red[tid] = local;
    __syncthreads();
    for (int s2 = 128; s2 > 0; s2 >>= 1) {
        if (tid < s2) red[tid] += red[tid + s2];
        __syncthreads();
    }
    float inv = 1.0f / red[0];
    for (int i = tid; i < 1681; i += 256) {
        int rr = i / 41, cc = i - rr * 41;
        out[c * 1681 + i] = p[(size_t)(r0 + rr) * SS + c0 + cc] * inv;
    }
}

// ---------------------------------------------------------------------------
extern "C" void kernel_launch(void* const* d_in, const int* in_sizes, int n_in,
                              void* d_out, int out_size, void* d_ws,
                              size_t ws_size, hipStream_t stream) {
    const float* lms = (const float*)d_in[0];
    const float* fuse = (const float*)d_in[1];
    char* ws = (char*)d_ws;
    float2* Zf = (float2*)ws;                                   // 64 MB: 8 planes
    float2* Wb = (float2*)(ws + ((size_t)64 << 20));            // 32 MB: 4 planes
    float* psf = (float*)ws;                                    // 32 MB, reuses Zf
    ull* bm = (ull*)(ws + ((size_t)33 << 20));                  // 64 KB, dead Zf region
    float* outp = (float*)d_out;

    // 1. fused blur + pack + forward row-FFT -> Zf[c][y][kx]
    blur_fft_kernel<<<8192, 256, 0, stream>>>(lms, fuse, Zf);
    // 2. transpose -> Zf[c][kx][y]
    transpose_kernel<<<dim3(528, 8), 256, 0, stream>>>(Zf);
    // 3. fused col-FFT + Wiener + inverse-ky-FFT -> Wb[p][kx][y]
    fft2_wiener_kernel<<<2048, 256, 0, stream>>>(Zf, Wb);
    // 4. transpose -> Wb[p][y][kx]
    transpose_kernel<<<dim3(528, 4), 256, 0, stream>>>(Wb);
    // 5. inverse kx-FFT + shift/threshold/split/block-argmax
    ifft_final_kernel<<<4096, 256, 0, stream>>>(Wb, psf, bm);
    // 6. argmax finish + crop/normalize
    crop_kernel<<<8, 256, 0, stream>>>(psf, bm, outp);
}